// Round 1
// baseline (381.648 us; speedup 1.0000x reference)
//
#include <hip/hip_runtime.h>

#define BB 8
#define NN 256
#define FDIM 1024
#define HDIM 256
#define NSQ 65536            // NN*NN
#define ROWS 2048            // BB*NN
#define KSEL 39321           // int(0.6*NN*NN)

// ---------- helpers ----------
__device__ __forceinline__ unsigned fkey(float f) {
  unsigned u = __float_as_uint(f);
  return (u & 0x80000000u) ? ~u : (u | 0x80000000u);
}
__device__ __forceinline__ float finv(unsigned k) {
  unsigned u = (k & 0x80000000u) ? (k & 0x7fffffffu) : ~k;
  return __uint_as_float(u);
}

// ---------- K0: init stats ----------
__global__ void k_init(unsigned* maxkey, float* sumE, float* msum) {
  int t = threadIdx.x;
  if (t < BB) { maxkey[t] = 0u; sumE[t] = 0.f; msum[t] = 0.f; }
}

// ---------- K1: PRB = x@Wr^T + b1 ; PC = x@Wc^T ----------
// C(2048 x 512) tile 64x64, k-tile 16, 256 threads, 4x4 per thread.
__global__ __launch_bounds__(256) void k_gemm(const float* __restrict__ X,
                                              const float* __restrict__ W1,
                                              const float* __restrict__ b1,
                                              float* __restrict__ PRB,
                                              float* __restrict__ PC) {
  const int bm = blockIdx.x * 64;       // row tile
  const int bn = blockIdx.y * 64;       // col tile in [0,512)
  const int t = threadIdx.x;
  const int tn = t & 15, tm = t >> 4;   // tn->n (coalesced stores), tm->m
  __shared__ float As[16][68];          // [k][m], pad 68 (16B-aligned rows)
  __shared__ float Bs[16][68];          // [k][n]
  const int halfoff = (bn >= 256) ? 1024 : 0;
  const int hbase = bn & 255;
  const int ar = t >> 2;                // 0..63
  const int ac = (t & 3) * 4;           // 0,4,8,12
  float acc[4][4] = {};
  for (int k0 = 0; k0 < FDIM; k0 += 16) {
    float4 av = *(const float4*)&X[(bm + ar) * FDIM + k0 + ac];
    float4 bv = *(const float4*)&W1[(hbase + ar) * (2 * FDIM) + halfoff + k0 + ac];
    As[ac + 0][ar] = av.x; As[ac + 1][ar] = av.y; As[ac + 2][ar] = av.z; As[ac + 3][ar] = av.w;
    Bs[ac + 0][ar] = bv.x; Bs[ac + 1][ar] = bv.y; Bs[ac + 2][ar] = bv.z; Bs[ac + 3][ar] = bv.w;
    __syncthreads();
#pragma unroll
    for (int kk = 0; kk < 16; ++kk) {
      float4 a = *(const float4*)&As[kk][tm * 4];
      float4 b = *(const float4*)&Bs[kk][tn * 4];
      acc[0][0] += a.x * b.x; acc[0][1] += a.x * b.y; acc[0][2] += a.x * b.z; acc[0][3] += a.x * b.w;
      acc[1][0] += a.y * b.x; acc[1][1] += a.y * b.y; acc[1][2] += a.y * b.z; acc[1][3] += a.y * b.w;
      acc[2][0] += a.z * b.x; acc[2][1] += a.z * b.y; acc[2][2] += a.z * b.z; acc[2][3] += a.z * b.w;
      acc[3][0] += a.w * b.x; acc[3][1] += a.w * b.y; acc[3][2] += a.w * b.z; acc[3][3] += a.w * b.w;
    }
    __syncthreads();
  }
  const int nq = bn + tn * 4;
  if (nq < 256) {
    float4 bias = *(const float4*)&b1[nq];
#pragma unroll
    for (int i = 0; i < 4; ++i) {
      float4 v = make_float4(acc[i][0] + bias.x, acc[i][1] + bias.y,
                             acc[i][2] + bias.z, acc[i][3] + bias.w);
      *(float4*)&PRB[(bm + tm * 4 + i) * HDIM + nq] = v;
    }
  } else {
#pragma unroll
    for (int i = 0; i < 4; ++i) {
      float4 v = make_float4(acc[i][0], acc[i][1], acc[i][2], acc[i][3]);
      *(float4*)&PC[(bm + tm * 4 + i) * HDIM + (nq - 256)] = v;
    }
  }
}

// ---------- K2: edge[b,i,j] = sum_h relu(PRB[b,i,h]+PC[b,j,h])*W2[h] + b2 ----------
// 64x64 (i,j) tile per block, h chunked by 64, 4x4 per thread.
__global__ __launch_bounds__(256) void k_edge(const float* __restrict__ PRB,
                                              const float* __restrict__ PC,
                                              const float* __restrict__ W2,
                                              const float* __restrict__ b2,
                                              float* __restrict__ edge) {
  const int b = blockIdx.z;
  const int i0 = blockIdx.y * 64, j0 = blockIdx.x * 64;
  const int t = threadIdx.x;
  const int tn = t & 15, tm = t >> 4;
  __shared__ float prs[64][68];   // [h][i]
  __shared__ float pcs[64][68];   // [h][j]
  __shared__ float w2s[HDIM];
  w2s[t] = W2[t];
  float acc[4][4] = {};
  for (int h0 = 0; h0 < HDIM; h0 += 64) {
    __syncthreads();
#pragma unroll
    for (int s = 0; s < 4; ++s) {
      int r = (t >> 4) + s * 16;
      int c0 = (t & 15) * 4;
      float4 v = *(const float4*)&PRB[(b * NN + i0 + r) * HDIM + h0 + c0];
      prs[c0 + 0][r] = v.x; prs[c0 + 1][r] = v.y; prs[c0 + 2][r] = v.z; prs[c0 + 3][r] = v.w;
      float4 u = *(const float4*)&PC[(b * NN + j0 + r) * HDIM + h0 + c0];
      pcs[c0 + 0][r] = u.x; pcs[c0 + 1][r] = u.y; pcs[c0 + 2][r] = u.z; pcs[c0 + 3][r] = u.w;
    }
    __syncthreads();
#pragma unroll 8
    for (int h = 0; h < 64; ++h) {
      float w = w2s[h0 + h];
      float4 a = *(const float4*)&prs[h][tm * 4];
      float4 c = *(const float4*)&pcs[h][tn * 4];
      float ai[4] = {a.x, a.y, a.z, a.w};
      float cj[4] = {c.x, c.y, c.z, c.w};
#pragma unroll
      for (int i = 0; i < 4; ++i)
#pragma unroll
        for (int j = 0; j < 4; ++j)
          acc[i][j] += fmaxf(ai[i] + cj[j], 0.f) * w;
    }
  }
  const float bias = b2[0];
#pragma unroll
  for (int i = 0; i < 4; ++i) {
    float4 v = make_float4(acc[i][0] + bias, acc[i][1] + bias,
                           acc[i][2] + bias, acc[i][3] + bias);
    *(float4*)&edge[b * NSQ + (i0 + tm * 4 + i) * NN + j0 + tn * 4] = v;
  }
}

// ---------- reductions over each batch row of 65536 ----------
__device__ __forceinline__ float blockReduceMax(float v, float* wm) {
  for (int off = 32; off > 0; off >>= 1) v = fmaxf(v, __shfl_down(v, off));
  int lane = threadIdx.x & 63, wid = threadIdx.x >> 6;
  if (lane == 0) wm[wid] = v;
  __syncthreads();
  return fmaxf(fmaxf(wm[0], wm[1]), fmaxf(wm[2], wm[3]));
}
__device__ __forceinline__ float blockReduceSum(float v, float* wm) {
  for (int off = 32; off > 0; off >>= 1) v += __shfl_down(v, off);
  int lane = threadIdx.x & 63, wid = threadIdx.x >> 6;
  if (lane == 0) wm[wid] = v;
  __syncthreads();
  return wm[0] + wm[1] + wm[2] + wm[3];
}

__global__ __launch_bounds__(256) void k_max(const float* __restrict__ edge,
                                             unsigned* __restrict__ maxkey) {
  const int b = blockIdx.y;
  const float* p = edge + b * NSQ + blockIdx.x * 2048 + threadIdx.x * 8;
  float4 v0 = *(const float4*)&p[0];
  float4 v1 = *(const float4*)&p[4];
  float m = fmaxf(fmaxf(fmaxf(v0.x, v0.y), fmaxf(v0.z, v0.w)),
                  fmaxf(fmaxf(v1.x, v1.y), fmaxf(v1.z, v1.w)));
  __shared__ float wm[4];
  m = blockReduceMax(m, wm);
  if (threadIdx.x == 0) atomicMax(&maxkey[b], fkey(m));
}

__global__ __launch_bounds__(256) void k_expsum(const float* __restrict__ edge,
                                                const unsigned* __restrict__ maxkey,
                                                float* __restrict__ sumE) {
  const int b = blockIdx.y;
  const float mx = finv(maxkey[b]);
  const float* p = edge + b * NSQ + blockIdx.x * 2048 + threadIdx.x * 8;
  float s = 0.f;
#pragma unroll
  for (int i = 0; i < 8; i += 4) {
    float4 v = *(const float4*)&p[i];
    s += __expf((v.x - mx) * 2.f) + __expf((v.y - mx) * 2.f)
       + __expf((v.z - mx) * 2.f) + __expf((v.w - mx) * 2.f);
  }
  __shared__ float wm[4];
  s = blockReduceSum(s, wm);
  if (threadIdx.x == 0) atomicAdd(&sumE[b], s);
}

__global__ __launch_bounds__(256) void k_soft(const float* __restrict__ edge,
                                              const unsigned* __restrict__ maxkey,
                                              const float* __restrict__ sumE,
                                              float* __restrict__ soft) {
  const int b = blockIdx.y;
  const float mx = finv(maxkey[b]);
  const float Z = sumE[b];
  const int off = b * NSQ + blockIdx.x * 2048 + threadIdx.x * 8;
#pragma unroll
  for (int i = 0; i < 8; i += 4) {
    float4 v = *(const float4*)&edge[off + i];
    float4 o = make_float4(__expf((v.x - mx) * 2.f) / Z, __expf((v.y - mx) * 2.f) / Z,
                           __expf((v.z - mx) * 2.f) / Z, __expf((v.w - mx) * 2.f) / Z);
    *(float4*)&soft[off + i] = o;
  }
}

// ---------- K5: exact k-th largest via 4-pass radix select on uint bits ----------
__global__ __launch_bounds__(256) void k_select(const float* __restrict__ soft,
                                                unsigned* __restrict__ thr) {
  const int b = blockIdx.x;
  const float* p = soft + b * NSQ;
  __shared__ unsigned hist[256];
  __shared__ unsigned sh_prefix;
  __shared__ int sh_k;
  const int t = threadIdx.x;
  if (t == 0) { sh_prefix = 0u; sh_k = KSEL; }
  for (int shift = 24; shift >= 0; shift -= 8) {
    hist[t] = 0u;
    __syncthreads();
    const unsigned prefix = sh_prefix;
    const unsigned himask = (shift == 24) ? 0u : (0xFFFFFFFFu << (shift + 8));
    for (int idx = t; idx < NSQ; idx += 256) {
      unsigned u = __float_as_uint(p[idx]);   // positive floats: uint order == float order
      if ((u & himask) == prefix) atomicAdd(&hist[(u >> shift) & 255u], 1u);
    }
    __syncthreads();
    if (t == 0) {
      int kk = sh_k;
      unsigned cum = 0;
      int d = 255;
      for (; d >= 0; --d) { cum += hist[d]; if ((int)cum >= kk) break; }
      sh_k = kk - (int)(cum - hist[d]);
      sh_prefix = prefix | ((unsigned)d << shift);
    }
    __syncthreads();
  }
  if (t == 0) thr[b] = sh_prefix;
}

__global__ __launch_bounds__(256) void k_msum(const float* __restrict__ soft,
                                              const unsigned* __restrict__ thr,
                                              float* __restrict__ msum) {
  const int b = blockIdx.y;
  const float th = __uint_as_float(thr[b]);
  const float* p = soft + b * NSQ + blockIdx.x * 2048 + threadIdx.x * 8;
  float s = 0.f;
#pragma unroll
  for (int i = 0; i < 8; i += 4) {
    float4 v = *(const float4*)&p[i];
    s += (v.x >= th ? v.x : 0.f) + (v.y >= th ? v.y : 0.f)
       + (v.z >= th ? v.z : 0.f) + (v.w >= th ? v.w : 0.f);
  }
  __shared__ float wm[4];
  s = blockReduceSum(s, wm);
  if (threadIdx.x == 0) atomicAdd(&msum[b], s);
}

__global__ __launch_bounds__(256) void k_final(const float* __restrict__ soft,
                                               const unsigned* __restrict__ thr,
                                               const float* __restrict__ msum,
                                               float* __restrict__ causal,
                                               float* __restrict__ conf) {
  const int b = blockIdx.y;
  const float th = __uint_as_float(thr[b]);
  const float denom = msum[b] + 1e-12f;
  const int off = b * NSQ + blockIdx.x * 2048 + threadIdx.x * 8;
#pragma unroll
  for (int i = 0; i < 8; i += 4) {
    float4 v = *(const float4*)&soft[off + i];
    float cx = v.x >= th ? v.x / denom : 0.f;
    float cy = v.y >= th ? v.y / denom : 0.f;
    float cz = v.z >= th ? v.z / denom : 0.f;
    float cw = v.w >= th ? v.w / denom : 0.f;
    *(float4*)&causal[off + i] = make_float4(cx, cy, cz, cw);
    *(float4*)&conf[off + i]   = make_float4(1.f - cx, 1.f - cy, 1.f - cz, 1.f - cw);
  }
}

extern "C" void kernel_launch(void* const* d_in, const int* in_sizes, int n_in,
                              void* d_out, int out_size, void* d_ws, size_t ws_size,
                              hipStream_t stream) {
  const float* x  = (const float*)d_in[0];
  const float* W1 = (const float*)d_in[1];
  const float* b1 = (const float*)d_in[2];
  const float* W2 = (const float*)d_in[3];
  const float* b2 = (const float*)d_in[4];

  float* out = (float*)d_out;
  float* causal = out;                 // 524288
  float* conf   = out + 1 * 524288;    // 524288
  float* edge   = out + 2 * 524288;    // 524288
  float* soft   = out + 3 * 524288;    // 524288

  float* ws = (float*)d_ws;
  float* PRB = ws;                     // 524288 floats
  float* PC  = ws + 524288;            // 524288 floats
  unsigned* maxkey = (unsigned*)(ws + 1048576);   // 8
  float*    sumE   = ws + 1048576 + 8;            // 8
  unsigned* thr    = (unsigned*)(ws + 1048576 + 16); // 8
  float*    msum   = ws + 1048576 + 24;           // 8

  k_init<<<1, 64, 0, stream>>>(maxkey, sumE, msum);
  k_gemm<<<dim3(32, 8), 256, 0, stream>>>(x, W1, b1, PRB, PC);
  k_edge<<<dim3(4, 4, 8), 256, 0, stream>>>(PRB, PC, W2, b2, edge);
  k_max<<<dim3(32, 8), 256, 0, stream>>>(edge, maxkey);
  k_expsum<<<dim3(32, 8), 256, 0, stream>>>(edge, maxkey, sumE);
  k_soft<<<dim3(32, 8), 256, 0, stream>>>(edge, maxkey, sumE, soft);
  k_select<<<8, 256, 0, stream>>>(soft, thr);
  k_msum<<<dim3(32, 8), 256, 0, stream>>>(soft, thr, msum);
  k_final<<<dim3(32, 8), 256, 0, stream>>>(soft, thr, msum, causal, conf);
}

// Round 2
// 281.281 us; speedup vs baseline: 1.3568x; 1.3568x over previous
//
#include <hip/hip_runtime.h>

#define BB 8
#define NN 256
#define FDIM 1024
#define HDIM 256
#define NSQ 65536            // NN*NN
#define ROWS 2048            // BB*NN
#define KSEL 39321           // int(0.6*NN*NN)

// ---------- helpers ----------
__device__ __forceinline__ unsigned fkey(float f) {
  unsigned u = __float_as_uint(f);
  return (u & 0x80000000u) ? ~u : (u | 0x80000000u);
}
__device__ __forceinline__ float finv(unsigned k) {
  unsigned u = (k & 0x80000000u) ? (k & 0x7fffffffu) : ~k;
  return __uint_as_float(u);
}

// ---------- K0: zero histogram + stats ----------
// grid 512 x 256 threads, uint4 each -> exactly 524288 uints (2 MB)
__global__ __launch_bounds__(256) void k_init(unsigned* __restrict__ hist,
                                              unsigned* maxkey, float* sumE, float* msum) {
  int idx = blockIdx.x * 256 + threadIdx.x;
  ((uint4*)hist)[idx] = make_uint4(0u, 0u, 0u, 0u);
  if (blockIdx.x == 0 && threadIdx.x < BB) {
    maxkey[threadIdx.x] = 0u; sumE[threadIdx.x] = 0.f; msum[threadIdx.x] = 0.f;
  }
}

// ---------- K1: PRB = x@Wr^T + b1 ; PC = x@Wc^T ----------
__global__ __launch_bounds__(256) void k_gemm(const float* __restrict__ X,
                                              const float* __restrict__ W1,
                                              const float* __restrict__ b1,
                                              float* __restrict__ PRB,
                                              float* __restrict__ PC) {
  const int bm = blockIdx.x * 64;
  const int bn = blockIdx.y * 64;
  const int t = threadIdx.x;
  const int tn = t & 15, tm = t >> 4;
  __shared__ float As[16][68];
  __shared__ float Bs[16][68];
  const int halfoff = (bn >= 256) ? 1024 : 0;
  const int hbase = bn & 255;
  const int ar = t >> 2;
  const int ac = (t & 3) * 4;
  float acc[4][4] = {};
  for (int k0 = 0; k0 < FDIM; k0 += 16) {
    float4 av = *(const float4*)&X[(bm + ar) * FDIM + k0 + ac];
    float4 bv = *(const float4*)&W1[(hbase + ar) * (2 * FDIM) + halfoff + k0 + ac];
    As[ac + 0][ar] = av.x; As[ac + 1][ar] = av.y; As[ac + 2][ar] = av.z; As[ac + 3][ar] = av.w;
    Bs[ac + 0][ar] = bv.x; Bs[ac + 1][ar] = bv.y; Bs[ac + 2][ar] = bv.z; Bs[ac + 3][ar] = bv.w;
    __syncthreads();
#pragma unroll
    for (int kk = 0; kk < 16; ++kk) {
      float4 a = *(const float4*)&As[kk][tm * 4];
      float4 b = *(const float4*)&Bs[kk][tn * 4];
      acc[0][0] += a.x * b.x; acc[0][1] += a.x * b.y; acc[0][2] += a.x * b.z; acc[0][3] += a.x * b.w;
      acc[1][0] += a.y * b.x; acc[1][1] += a.y * b.y; acc[1][2] += a.y * b.z; acc[1][3] += a.y * b.w;
      acc[2][0] += a.z * b.x; acc[2][1] += a.z * b.y; acc[2][2] += a.z * b.z; acc[2][3] += a.z * b.w;
      acc[3][0] += a.w * b.x; acc[3][1] += a.w * b.y; acc[3][2] += a.w * b.z; acc[3][3] += a.w * b.w;
    }
    __syncthreads();
  }
  const int nq = bn + tn * 4;
  if (nq < 256) {
    float4 bias = *(const float4*)&b1[nq];
#pragma unroll
    for (int i = 0; i < 4; ++i) {
      float4 v = make_float4(acc[i][0] + bias.x, acc[i][1] + bias.y,
                             acc[i][2] + bias.z, acc[i][3] + bias.w);
      *(float4*)&PRB[(bm + tm * 4 + i) * HDIM + nq] = v;
    }
  } else {
#pragma unroll
    for (int i = 0; i < 4; ++i) {
      float4 v = make_float4(acc[i][0], acc[i][1], acc[i][2], acc[i][3]);
      *(float4*)&PC[(bm + tm * 4 + i) * HDIM + (nq - 256)] = v;
    }
  }
}

// ---------- K2: edge[b,i,j] = sum_h relu(PRB[b,i,h]+PC[b,j,h])*W2[h] + b2 ----------
__global__ __launch_bounds__(256) void k_edge(const float* __restrict__ PRB,
                                              const float* __restrict__ PC,
                                              const float* __restrict__ W2,
                                              const float* __restrict__ b2,
                                              float* __restrict__ edge) {
  const int b = blockIdx.z;
  const int i0 = blockIdx.y * 64, j0 = blockIdx.x * 64;
  const int t = threadIdx.x;
  const int tn = t & 15, tm = t >> 4;
  __shared__ float prs[64][68];
  __shared__ float pcs[64][68];
  __shared__ float w2s[HDIM];
  w2s[t] = W2[t];
  float acc[4][4] = {};
  for (int h0 = 0; h0 < HDIM; h0 += 64) {
    __syncthreads();
#pragma unroll
    for (int s = 0; s < 4; ++s) {
      int r = (t >> 4) + s * 16;
      int c0 = (t & 15) * 4;
      float4 v = *(const float4*)&PRB[(b * NN + i0 + r) * HDIM + h0 + c0];
      prs[c0 + 0][r] = v.x; prs[c0 + 1][r] = v.y; prs[c0 + 2][r] = v.z; prs[c0 + 3][r] = v.w;
      float4 u = *(const float4*)&PC[(b * NN + j0 + r) * HDIM + h0 + c0];
      pcs[c0 + 0][r] = u.x; pcs[c0 + 1][r] = u.y; pcs[c0 + 2][r] = u.z; pcs[c0 + 3][r] = u.w;
    }
    __syncthreads();
#pragma unroll 8
    for (int h = 0; h < 64; ++h) {
      float w = w2s[h0 + h];
      float4 a = *(const float4*)&prs[h][tm * 4];
      float4 c = *(const float4*)&pcs[h][tn * 4];
      float ai[4] = {a.x, a.y, a.z, a.w};
      float cj[4] = {c.x, c.y, c.z, c.w};
#pragma unroll
      for (int i = 0; i < 4; ++i)
#pragma unroll
        for (int j = 0; j < 4; ++j)
          acc[i][j] += fmaxf(ai[i] + cj[j], 0.f) * w;
    }
  }
  const float bias = b2[0];
#pragma unroll
  for (int i = 0; i < 4; ++i) {
    float4 v = make_float4(acc[i][0] + bias, acc[i][1] + bias,
                           acc[i][2] + bias, acc[i][3] + bias);
    *(float4*)&edge[b * NSQ + (i0 + tm * 4 + i) * NN + j0 + tn * 4] = v;
  }
}

// ---------- reductions ----------
__device__ __forceinline__ float blockReduceMax(float v, float* wm) {
  for (int off = 32; off > 0; off >>= 1) v = fmaxf(v, __shfl_down(v, off));
  int lane = threadIdx.x & 63, wid = threadIdx.x >> 6;
  if (lane == 0) wm[wid] = v;
  __syncthreads();
  return fmaxf(fmaxf(wm[0], wm[1]), fmaxf(wm[2], wm[3]));
}
__device__ __forceinline__ float blockReduceSum(float v, float* wm) {
  for (int off = 32; off > 0; off >>= 1) v += __shfl_down(v, off);
  int lane = threadIdx.x & 63, wid = threadIdx.x >> 6;
  if (lane == 0) wm[wid] = v;
  __syncthreads();
  return wm[0] + wm[1] + wm[2] + wm[3];
}

__global__ __launch_bounds__(256) void k_max(const float* __restrict__ edge,
                                             unsigned* __restrict__ maxkey) {
  const int b = blockIdx.y;
  const float* p = edge + b * NSQ + blockIdx.x * 2048 + threadIdx.x * 8;
  float4 v0 = *(const float4*)&p[0];
  float4 v1 = *(const float4*)&p[4];
  float m = fmaxf(fmaxf(fmaxf(v0.x, v0.y), fmaxf(v0.z, v0.w)),
                  fmaxf(fmaxf(v1.x, v1.y), fmaxf(v1.z, v1.w)));
  __shared__ float wm[4];
  m = blockReduceMax(m, wm);
  if (threadIdx.x == 0) atomicMax(&maxkey[b], fkey(m));
}

__global__ __launch_bounds__(256) void k_expsum(const float* __restrict__ edge,
                                                const unsigned* __restrict__ maxkey,
                                                float* __restrict__ sumE) {
  const int b = blockIdx.y;
  const float mx = finv(maxkey[b]);
  const float* p = edge + b * NSQ + blockIdx.x * 2048 + threadIdx.x * 8;
  float s = 0.f;
#pragma unroll
  for (int i = 0; i < 8; i += 4) {
    float4 v = *(const float4*)&p[i];
    s += __expf((v.x - mx) * 2.f) + __expf((v.y - mx) * 2.f)
       + __expf((v.z - mx) * 2.f) + __expf((v.w - mx) * 2.f);
  }
  __shared__ float wm[4];
  s = blockReduceSum(s, wm);
  if (threadIdx.x == 0) atomicAdd(&sumE[b], s);
}

// ---------- K4: soft = exp((e-mx)*2)/Z, fused top-16-bit histogram ----------
__global__ __launch_bounds__(256) void k_soft(const float* __restrict__ edge,
                                              const unsigned* __restrict__ maxkey,
                                              const float* __restrict__ sumE,
                                              float* __restrict__ soft,
                                              unsigned* __restrict__ hist) {
  const int b = blockIdx.y;
  const float mx = finv(maxkey[b]);
  const float Z = sumE[b];
  const int off = b * NSQ + blockIdx.x * 2048 + threadIdx.x * 8;
  unsigned* h = hist + b * NSQ;
#pragma unroll
  for (int i = 0; i < 8; i += 4) {
    float4 v = *(const float4*)&edge[off + i];
    float4 o = make_float4(__expf((v.x - mx) * 2.f) / Z, __expf((v.y - mx) * 2.f) / Z,
                           __expf((v.z - mx) * 2.f) / Z, __expf((v.w - mx) * 2.f) / Z);
    *(float4*)&soft[off + i] = o;
    atomicAdd(&h[__float_as_uint(o.x) >> 16], 1u);
    atomicAdd(&h[__float_as_uint(o.y) >> 16], 1u);
    atomicAdd(&h[__float_as_uint(o.z) >> 16], 1u);
    atomicAdd(&h[__float_as_uint(o.w) >> 16], 1u);
  }
}

// ---------- K5: find bin containing k-th largest over a 65536-bin histogram ----------
// one block per batch; also zeroes the histogram afterward (for reuse by pass 2).
__global__ __launch_bounds__(256) void k_scan(unsigned* __restrict__ hist,
                                              const int* __restrict__ kin,
                                              unsigned* __restrict__ pref,
                                              int* __restrict__ kout) {
  const int b = blockIdx.x;
  const int t = threadIdx.x;
  unsigned* h = hist + b * NSQ;
  // chunk t covers bins [t*256, (t+1)*256)
  unsigned csum = 0;
  for (int i = 0; i < 256; ++i) csum += h[t * 256 + i];
  __shared__ unsigned cs[256];
  __shared__ unsigned S[256];     // suffix sums: S[c] = sum of cs[c'] for c' > c
  cs[t] = csum;
  __syncthreads();
  if (t == 0) {
    unsigned acc = 0;
    for (int c = 255; c >= 0; --c) { S[c] = acc; acc += cs[c]; }
  }
  __syncthreads();
  const int k = kin ? kin[b] : KSEL;
  if ((int)S[t] < k && (int)(S[t] + cs[t]) >= k) {   // exactly one thread
    unsigned cum = S[t];
    for (int i = 255; i >= 0; --i) {
      unsigned c = h[t * 256 + i];
      cum += c;
      if ((int)cum >= k) {
        pref[b] = (unsigned)(t * 256 + i);
        kout[b] = k - (int)(cum - c);
        break;
      }
    }
  }
  __syncthreads();
  for (int i = 0; i < 256; ++i) h[t * 256 + i] = 0u;   // reset for pass 2
}

// ---------- K6: low-16-bit histogram of prefix-matching elements ----------
__global__ __launch_bounds__(256) void k_hist2(const float* __restrict__ soft,
                                               const unsigned* __restrict__ pref1,
                                               unsigned* __restrict__ hist) {
  const int b = blockIdx.y;
  const unsigned p1 = pref1[b];
  const float* p = soft + b * NSQ + blockIdx.x * 2048 + threadIdx.x * 8;
  unsigned* h = hist + b * NSQ;
#pragma unroll
  for (int i = 0; i < 8; i += 4) {
    float4 v = *(const float4*)&p[i];
    unsigned ux = __float_as_uint(v.x), uy = __float_as_uint(v.y);
    unsigned uz = __float_as_uint(v.z), uw = __float_as_uint(v.w);
    if ((ux >> 16) == p1) atomicAdd(&h[ux & 0xFFFFu], 1u);
    if ((uy >> 16) == p1) atomicAdd(&h[uy & 0xFFFFu], 1u);
    if ((uz >> 16) == p1) atomicAdd(&h[uz & 0xFFFFu], 1u);
    if ((uw >> 16) == p1) atomicAdd(&h[uw & 0xFFFFu], 1u);
  }
}

__device__ __forceinline__ float thr_from(const unsigned* pref1, const unsigned* pref2, int b) {
  return __uint_as_float((pref1[b] << 16) | pref2[b]);
}

__global__ __launch_bounds__(256) void k_msum(const float* __restrict__ soft,
                                              const unsigned* __restrict__ pref1,
                                              const unsigned* __restrict__ pref2,
                                              float* __restrict__ msum) {
  const int b = blockIdx.y;
  const float th = thr_from(pref1, pref2, b);
  const float* p = soft + b * NSQ + blockIdx.x * 2048 + threadIdx.x * 8;
  float s = 0.f;
#pragma unroll
  for (int i = 0; i < 8; i += 4) {
    float4 v = *(const float4*)&p[i];
    s += (v.x >= th ? v.x : 0.f) + (v.y >= th ? v.y : 0.f)
       + (v.z >= th ? v.z : 0.f) + (v.w >= th ? v.w : 0.f);
  }
  __shared__ float wm[4];
  s = blockReduceSum(s, wm);
  if (threadIdx.x == 0) atomicAdd(&msum[b], s);
}

__global__ __launch_bounds__(256) void k_final(const float* __restrict__ soft,
                                               const unsigned* __restrict__ pref1,
                                               const unsigned* __restrict__ pref2,
                                               const float* __restrict__ msum,
                                               float* __restrict__ causal,
                                               float* __restrict__ conf) {
  const int b = blockIdx.y;
  const float th = thr_from(pref1, pref2, b);
  const float denom = msum[b] + 1e-12f;
  const int off = b * NSQ + blockIdx.x * 2048 + threadIdx.x * 8;
#pragma unroll
  for (int i = 0; i < 8; i += 4) {
    float4 v = *(const float4*)&soft[off + i];
    float cx = v.x >= th ? v.x / denom : 0.f;
    float cy = v.y >= th ? v.y / denom : 0.f;
    float cz = v.z >= th ? v.z / denom : 0.f;
    float cw = v.w >= th ? v.w / denom : 0.f;
    *(float4*)&causal[off + i] = make_float4(cx, cy, cz, cw);
    *(float4*)&conf[off + i]   = make_float4(1.f - cx, 1.f - cy, 1.f - cz, 1.f - cw);
  }
}

extern "C" void kernel_launch(void* const* d_in, const int* in_sizes, int n_in,
                              void* d_out, int out_size, void* d_ws, size_t ws_size,
                              hipStream_t stream) {
  const float* x  = (const float*)d_in[0];
  const float* W1 = (const float*)d_in[1];
  const float* b1 = (const float*)d_in[2];
  const float* W2 = (const float*)d_in[3];
  const float* b2 = (const float*)d_in[4];

  float* out = (float*)d_out;
  float* causal = out;                 // 524288
  float* conf   = out + 1 * 524288;    // 524288
  float* edge   = out + 2 * 524288;    // 524288
  float* soft   = out + 3 * 524288;    // 524288

  float* ws = (float*)d_ws;
  float*    PRB    = ws;                                  // 524288 floats
  float*    PC     = ws + 524288;                         // 524288 floats
  unsigned* hist   = (unsigned*)(ws + 1048576);           // 524288 uints (8 x 65536)
  unsigned* maxkey = (unsigned*)(ws + 1572864);           // 8
  float*    sumE   = ws + 1572864 + 8;                    // 8
  unsigned* pref1  = (unsigned*)(ws + 1572864 + 16);      // 8
  int*      k2     = (int*)(ws + 1572864 + 24);           // 8
  unsigned* pref2  = (unsigned*)(ws + 1572864 + 32);      // 8
  int*      kdump  = (int*)(ws + 1572864 + 40);           // 8
  float*    msum   = ws + 1572864 + 48;                   // 8

  k_init<<<512, 256, 0, stream>>>(hist, maxkey, sumE, msum);
  k_gemm<<<dim3(32, 8), 256, 0, stream>>>(x, W1, b1, PRB, PC);
  k_edge<<<dim3(4, 4, 8), 256, 0, stream>>>(PRB, PC, W2, b2, edge);
  k_max<<<dim3(32, 8), 256, 0, stream>>>(edge, maxkey);
  k_expsum<<<dim3(32, 8), 256, 0, stream>>>(edge, maxkey, sumE);
  k_soft<<<dim3(32, 8), 256, 0, stream>>>(edge, maxkey, sumE, soft, hist);
  k_scan<<<8, 256, 0, stream>>>(hist, nullptr, pref1, k2);
  k_hist2<<<dim3(32, 8), 256, 0, stream>>>(soft, pref1, hist);
  k_scan<<<8, 256, 0, stream>>>(hist, k2, pref2, kdump);
  k_msum<<<dim3(32, 8), 256, 0, stream>>>(soft, pref1, pref2, msum);
  k_final<<<dim3(32, 8), 256, 0, stream>>>(soft, pref1, pref2, msum, causal, conf);
}

// Round 4
// 157.482 us; speedup vs baseline: 2.4234x; 1.7861x over previous
//
#include <hip/hip_runtime.h>

#define BB 8
#define NN 256
#define FDIM 1024
#define HDIM 256
#define NSQ 65536            // NN*NN
#define ROWS 2048            // BB*NN
#define KSEL 39321           // int(0.6*NN*NN)

typedef short s16x8 __attribute__((ext_vector_type(8)));
typedef float f32x4 __attribute__((ext_vector_type(4)));

// ---------- helpers ----------
__device__ __forceinline__ unsigned fkey(float f) {
  unsigned u = __float_as_uint(f);
  return (u & 0x80000000u) ? ~u : (u | 0x80000000u);
}
__device__ __forceinline__ float finv(unsigned k) {
  unsigned u = (k & 0x80000000u) ? (k & 0x7fffffffu) : ~k;
  return __uint_as_float(u);
}
__device__ __forceinline__ unsigned short f2bf(float f) {   // RNE
  unsigned u = __float_as_uint(f);
  unsigned r = (u + 0x7fffu + ((u >> 16) & 1u)) >> 16;
  return (unsigned short)r;
}

// ---------- K0: zero hist1/hist2/hist3 + stats (67656 uints) ----------
#define NZERO 67656
__global__ __launch_bounds__(256) void k_init(unsigned* __restrict__ z) {
  int idx = blockIdx.x * 256 + threadIdx.x;
  if (idx < NZERO) z[idx] = 0u;
}

// ---------- K1: bf16-MFMA GEMM: PRB = x@Wr^T + b1 ; PC = x@Wc^T ----------
// M=2048, N=512 (first 256 -> PRB, rest -> PC), K=1024.
// Block: 64x64 tile, 256 thr = 4 waves, each wave 32x32 via 2x2 mfma_16x16x32.
// K-chunk = 64 per iteration; mfma_16x16x32 consumes K=32 per call -> two
// MFMA groups per iteration at LDS k-offsets +0 and +32. (R3 bug: treated
// the intrinsic as K=16 and double-counted k.)
#define LDSW 72   // row stride in bf16 elems (64 + 8 pad); 144 B
__global__ __launch_bounds__(256) void k_gemm(const float* __restrict__ X,
                                              const float* __restrict__ W1,
                                              const float* __restrict__ b1,
                                              float* __restrict__ PRB,
                                              float* __restrict__ PC) {
  const int bm = blockIdx.x * 64;
  const int bn = blockIdx.y * 64;         // 0..511
  const int t = threadIdx.x;
  __shared__ short As[64 * LDSW];
  __shared__ short Bs[64 * LDSW];
  // staging map: row sr = t>>2 (0..63), cg = t&3 -> 16-float column group
  const int sr = t >> 2, cg = t & 3;
  const float* pa = X + (bm + sr) * FDIM + cg * 16;
  const float* pb = (bn < 256) ? (W1 + (bn + sr) * (2 * FDIM) + cg * 16)
                               : (W1 + (bn - 256 + sr) * (2 * FDIM) + FDIM + cg * 16);
  // wave/fragment map
  const int w = t >> 6, lane = t & 63;
  const int wm = (w >> 1) * 32, wn = (w & 1) * 32;
  const int q = lane >> 4, m16 = lane & 15;
  f32x4 acc[2][2] = {};
  for (int k0 = 0; k0 < FDIM; k0 += 64) {
    float4 a0 = *(const float4*)(pa + k0);
    float4 a1 = *(const float4*)(pa + k0 + 4);
    float4 a2 = *(const float4*)(pa + k0 + 8);
    float4 a3 = *(const float4*)(pa + k0 + 12);
    float4 b0 = *(const float4*)(pb + k0);
    float4 b1v = *(const float4*)(pb + k0 + 4);
    float4 b2v = *(const float4*)(pb + k0 + 8);
    float4 b3v = *(const float4*)(pb + k0 + 12);
    s16x8 avlo, avhi, bvlo, bvhi;
    avlo[0] = (short)f2bf(a0.x); avlo[1] = (short)f2bf(a0.y); avlo[2] = (short)f2bf(a0.z); avlo[3] = (short)f2bf(a0.w);
    avlo[4] = (short)f2bf(a1.x); avlo[5] = (short)f2bf(a1.y); avlo[6] = (short)f2bf(a1.z); avlo[7] = (short)f2bf(a1.w);
    avhi[0] = (short)f2bf(a2.x); avhi[1] = (short)f2bf(a2.y); avhi[2] = (short)f2bf(a2.z); avhi[3] = (short)f2bf(a2.w);
    avhi[4] = (short)f2bf(a3.x); avhi[5] = (short)f2bf(a3.y); avhi[6] = (short)f2bf(a3.z); avhi[7] = (short)f2bf(a3.w);
    bvlo[0] = (short)f2bf(b0.x); bvlo[1] = (short)f2bf(b0.y); bvlo[2] = (short)f2bf(b0.z); bvlo[3] = (short)f2bf(b0.w);
    bvlo[4] = (short)f2bf(b1v.x); bvlo[5] = (short)f2bf(b1v.y); bvlo[6] = (short)f2bf(b1v.z); bvlo[7] = (short)f2bf(b1v.w);
    bvhi[0] = (short)f2bf(b2v.x); bvhi[1] = (short)f2bf(b2v.y); bvhi[2] = (short)f2bf(b2v.z); bvhi[3] = (short)f2bf(b2v.w);
    bvhi[4] = (short)f2bf(b3v.x); bvhi[5] = (short)f2bf(b3v.y); bvhi[6] = (short)f2bf(b3v.z); bvhi[7] = (short)f2bf(b3v.w);
    __syncthreads();
    *(s16x8*)&As[sr * LDSW + cg * 16]     = avlo;
    *(s16x8*)&As[sr * LDSW + cg * 16 + 8] = avhi;
    *(s16x8*)&Bs[sr * LDSW + cg * 16]     = bvlo;
    *(s16x8*)&Bs[sr * LDSW + cg * 16 + 8] = bvhi;
    __syncthreads();
    // k local 0..31
    {
      s16x8 af0 = *(s16x8*)&As[(wm + m16) * LDSW + q * 8];
      s16x8 af1 = *(s16x8*)&As[(wm + 16 + m16) * LDSW + q * 8];
      s16x8 bf0 = *(s16x8*)&Bs[(wn + m16) * LDSW + q * 8];
      s16x8 bf1 = *(s16x8*)&Bs[(wn + 16 + m16) * LDSW + q * 8];
      acc[0][0] = __builtin_amdgcn_mfma_f32_16x16x32_bf16(af0, bf0, acc[0][0], 0, 0, 0);
      acc[0][1] = __builtin_amdgcn_mfma_f32_16x16x32_bf16(af0, bf1, acc[0][1], 0, 0, 0);
      acc[1][0] = __builtin_amdgcn_mfma_f32_16x16x32_bf16(af1, bf0, acc[1][0], 0, 0, 0);
      acc[1][1] = __builtin_amdgcn_mfma_f32_16x16x32_bf16(af1, bf1, acc[1][1], 0, 0, 0);
    }
    // k local 32..63
    {
      s16x8 af0 = *(s16x8*)&As[(wm + m16) * LDSW + 32 + q * 8];
      s16x8 af1 = *(s16x8*)&As[(wm + 16 + m16) * LDSW + 32 + q * 8];
      s16x8 bf0 = *(s16x8*)&Bs[(wn + m16) * LDSW + 32 + q * 8];
      s16x8 bf1 = *(s16x8*)&Bs[(wn + 16 + m16) * LDSW + 32 + q * 8];
      acc[0][0] = __builtin_amdgcn_mfma_f32_16x16x32_bf16(af0, bf0, acc[0][0], 0, 0, 0);
      acc[0][1] = __builtin_amdgcn_mfma_f32_16x16x32_bf16(af0, bf1, acc[0][1], 0, 0, 0);
      acc[1][0] = __builtin_amdgcn_mfma_f32_16x16x32_bf16(af1, bf0, acc[1][0], 0, 0, 0);
      acc[1][1] = __builtin_amdgcn_mfma_f32_16x16x32_bf16(af1, bf1, acc[1][1], 0, 0, 0);
    }
  }
  // epilogue: D lane map col=lane&15, row=(lane>>4)*4+reg
#pragma unroll
  for (int rt = 0; rt < 2; ++rt) {
#pragma unroll
    for (int ct = 0; ct < 2; ++ct) {
      const int hn = bn + wn + ct * 16 + m16;       // 0..511
      const int row0 = bm + wm + rt * 16 + q * 4;
      if (hn < 256) {
        const float bias = b1[hn];
#pragma unroll
        for (int i = 0; i < 4; ++i)
          PRB[(row0 + i) * HDIM + hn] = acc[rt][ct][i] + bias;
      } else {
#pragma unroll
        for (int i = 0; i < 4; ++i)
          PC[(row0 + i) * HDIM + (hn - 256)] = acc[rt][ct][i];
      }
    }
  }
}

// ---------- K2: edge[b,i,j] = sum_h relu(PRB[b,i,h]+PC[b,j,h])*W2[h] + b2 ----------
__global__ __launch_bounds__(256) void k_edge(const float* __restrict__ PRB,
                                              const float* __restrict__ PC,
                                              const float* __restrict__ W2,
                                              const float* __restrict__ b2,
                                              float* __restrict__ edge) {
  const int b = blockIdx.z;
  const int i0 = blockIdx.y * 64, j0 = blockIdx.x * 64;
  const int t = threadIdx.x;
  const int tn = t & 15, tm = t >> 4;
  __shared__ float prs[64][68];
  __shared__ float pcs[64][68];
  __shared__ float w2s[HDIM];
  w2s[t] = W2[t];
  float acc[4][4] = {};
  for (int h0 = 0; h0 < HDIM; h0 += 64) {
    __syncthreads();
#pragma unroll
    for (int s = 0; s < 4; ++s) {
      int r = (t >> 4) + s * 16;
      int c0 = (t & 15) * 4;
      float4 v = *(const float4*)&PRB[(b * NN + i0 + r) * HDIM + h0 + c0];
      prs[c0 + 0][r] = v.x; prs[c0 + 1][r] = v.y; prs[c0 + 2][r] = v.z; prs[c0 + 3][r] = v.w;
      float4 u = *(const float4*)&PC[(b * NN + j0 + r) * HDIM + h0 + c0];
      pcs[c0 + 0][r] = u.x; pcs[c0 + 1][r] = u.y; pcs[c0 + 2][r] = u.z; pcs[c0 + 3][r] = u.w;
    }
    __syncthreads();
#pragma unroll 8
    for (int h = 0; h < 64; ++h) {
      float w = w2s[h0 + h];
      float4 a = *(const float4*)&prs[h][tm * 4];
      float4 c = *(const float4*)&pcs[h][tn * 4];
      float ai[4] = {a.x, a.y, a.z, a.w};
      float cj[4] = {c.x, c.y, c.z, c.w};
#pragma unroll
      for (int i = 0; i < 4; ++i)
#pragma unroll
        for (int j = 0; j < 4; ++j)
          acc[i][j] += fmaxf(ai[i] + cj[j], 0.f) * w;
    }
  }
  const float bias = b2[0];
#pragma unroll
  for (int i = 0; i < 4; ++i) {
    float4 v = make_float4(acc[i][0] + bias, acc[i][1] + bias,
                           acc[i][2] + bias, acc[i][3] + bias);
    *(float4*)&edge[b * NSQ + (i0 + tm * 4 + i) * NN + j0 + tn * 4] = v;
  }
}

// ---------- reductions ----------
__device__ __forceinline__ float blockReduceMax(float v, float* wm) {
  for (int off = 32; off > 0; off >>= 1) v = fmaxf(v, __shfl_down(v, off));
  int lane = threadIdx.x & 63, wid = threadIdx.x >> 6;
  if (lane == 0) wm[wid] = v;
  __syncthreads();
  return fmaxf(fmaxf(wm[0], wm[1]), fmaxf(wm[2], wm[3]));
}
__device__ __forceinline__ float blockReduceSum(float v, float* wm) {
  for (int off = 32; off > 0; off >>= 1) v += __shfl_down(v, off);
  int lane = threadIdx.x & 63, wid = threadIdx.x >> 6;
  if (lane == 0) wm[wid] = v;
  __syncthreads();
  return wm[0] + wm[1] + wm[2] + wm[3];
}

__global__ __launch_bounds__(256) void k_max(const float* __restrict__ edge,
                                             unsigned* __restrict__ maxkey) {
  const int b = blockIdx.y;
  const float* p = edge + b * NSQ + blockIdx.x * 2048 + threadIdx.x * 8;
  float4 v0 = *(const float4*)&p[0];
  float4 v1 = *(const float4*)&p[4];
  float m = fmaxf(fmaxf(fmaxf(v0.x, v0.y), fmaxf(v0.z, v0.w)),
                  fmaxf(fmaxf(v1.x, v1.y), fmaxf(v1.z, v1.w)));
  __shared__ float wm[4];
  m = blockReduceMax(m, wm);
  if (threadIdx.x == 0) atomicMax(&maxkey[b], fkey(m));
}

// ---------- K4: expsum + level-1 histogram (top 12 bits of fkey) ----------
__global__ __launch_bounds__(256) void k_expsum(const float* __restrict__ edge,
                                                const unsigned* __restrict__ maxkey,
                                                float* __restrict__ sumE,
                                                unsigned* __restrict__ hist1) {
  const int b = blockIdx.y;
  const int t = threadIdx.x;
  __shared__ unsigned lh[4096];
#pragma unroll
  for (int i = 0; i < 16; ++i) lh[t + i * 256] = 0u;
  __syncthreads();
  const float mx = finv(maxkey[b]);
  const float* p = edge + b * NSQ + blockIdx.x * 2048 + t * 8;
  float s = 0.f;
#pragma unroll
  for (int i = 0; i < 8; i += 4) {
    float4 v = *(const float4*)&p[i];
    s += __expf((v.x - mx) * 2.f) + __expf((v.y - mx) * 2.f)
       + __expf((v.z - mx) * 2.f) + __expf((v.w - mx) * 2.f);
    atomicAdd(&lh[fkey(v.x) >> 20], 1u);
    atomicAdd(&lh[fkey(v.y) >> 20], 1u);
    atomicAdd(&lh[fkey(v.z) >> 20], 1u);
    atomicAdd(&lh[fkey(v.w) >> 20], 1u);
  }
  __shared__ float wm[4];
  s = blockReduceSum(s, wm);
  if (t == 0) atomicAdd(&sumE[b], s);
  __syncthreads();
  unsigned* g = hist1 + b * 4096;
#pragma unroll
  for (int i = 0; i < 16; ++i) {
    unsigned c = lh[t + i * 256];
    if (c) atomicAdd(&g[t + i * 256], c);
  }
}

// ---------- scan: find bin containing k-th largest (descending) ----------
template<int NB>
__global__ __launch_bounds__(256) void k_scan(const unsigned* __restrict__ hist,
                                              const int* __restrict__ kin, int kdef,
                                              unsigned* __restrict__ pref,
                                              int* __restrict__ kout) {
  const int b = blockIdx.x;
  const int t = threadIdx.x;
  constexpr int C = NB / 256;
  const unsigned* h = hist + b * NB;
  unsigned loc[C];
  unsigned cs = 0;
#pragma unroll
  for (int i = 0; i < C; ++i) { loc[i] = h[t * C + i]; cs += loc[i]; }
  __shared__ unsigned S[256];
  S[t] = cs;
  __syncthreads();
  for (int off = 1; off < 256; off <<= 1) {   // inclusive suffix sum
    unsigned u = (t + off < 256) ? S[t + off] : 0u;
    __syncthreads();
    S[t] += u;
    __syncthreads();
  }
  const int k = kin ? kin[b] : kdef;
  const int above = (int)(S[t] - cs);
  if (above < k && (int)S[t] >= k) {          // exactly one thread
    int cum = above;
    for (int i = C - 1; i >= 0; --i) {
      cum += (int)loc[i];
      if (cum >= k) {
        pref[b] = (unsigned)(t * C + i);
        kout[b] = k - (cum - (int)loc[i]);
        break;
      }
    }
  }
}

// ---------- level-2 histogram: bits 8..19 of fkey, among top-12 matches ----------
__global__ __launch_bounds__(256) void k_hist2(const float* __restrict__ edge,
                                               const unsigned* __restrict__ pref1,
                                               unsigned* __restrict__ hist2) {
  const int b = blockIdx.y;
  const int t = threadIdx.x;
  __shared__ unsigned lh[4096];
#pragma unroll
  for (int i = 0; i < 16; ++i) lh[t + i * 256] = 0u;
  __syncthreads();
  const unsigned p1 = pref1[b];
  const float* p = edge + b * NSQ + blockIdx.x * 2048 + t * 8;
#pragma unroll
  for (int i = 0; i < 8; i += 4) {
    float4 v = *(const float4*)&p[i];
    unsigned kx = fkey(v.x), ky = fkey(v.y), kz = fkey(v.z), kw = fkey(v.w);
    if ((kx >> 20) == p1) atomicAdd(&lh[(kx >> 8) & 0xFFFu], 1u);
    if ((ky >> 20) == p1) atomicAdd(&lh[(ky >> 8) & 0xFFFu], 1u);
    if ((kz >> 20) == p1) atomicAdd(&lh[(kz >> 8) & 0xFFFu], 1u);
    if ((kw >> 20) == p1) atomicAdd(&lh[(kw >> 8) & 0xFFFu], 1u);
  }
  __syncthreads();
  unsigned* g = hist2 + b * 4096;
#pragma unroll
  for (int i = 0; i < 16; ++i) {
    unsigned c = lh[t + i * 256];
    if (c) atomicAdd(&g[t + i * 256], c);
  }
}

// ---------- level-3 histogram: bits 0..7, among top-24 matches ----------
__global__ __launch_bounds__(256) void k_hist3(const float* __restrict__ edge,
                                               const unsigned* __restrict__ pref1,
                                               const unsigned* __restrict__ pref2,
                                               unsigned* __restrict__ hist3) {
  const int b = blockIdx.y;
  const int t = threadIdx.x;
  __shared__ unsigned lh[256];
  lh[t] = 0u;
  __syncthreads();
  const unsigned p24 = (pref1[b] << 12) | pref2[b];
  const float* p = edge + b * NSQ + blockIdx.x * 2048 + t * 8;
#pragma unroll
  for (int i = 0; i < 8; i += 4) {
    float4 v = *(const float4*)&p[i];
    unsigned kx = fkey(v.x), ky = fkey(v.y), kz = fkey(v.z), kw = fkey(v.w);
    if ((kx >> 8) == p24) atomicAdd(&lh[kx & 0xFFu], 1u);
    if ((ky >> 8) == p24) atomicAdd(&lh[ky & 0xFFu], 1u);
    if ((kz >> 8) == p24) atomicAdd(&lh[kz & 0xFFu], 1u);
    if ((kw >> 8) == p24) atomicAdd(&lh[kw & 0xFFu], 1u);
  }
  __syncthreads();
  unsigned* g = hist3 + b * 256;
  unsigned c = lh[t];
  if (c) atomicAdd(&g[t], c);
}

__device__ __forceinline__ float load_thr(const unsigned* p1, const unsigned* p2,
                                          const unsigned* p3, int b) {
  return finv((p1[b] << 20) | (p2[b] << 8) | p3[b]);
}

// ---------- soft = exp((e-mx)*2)/Z (write) + masked sum ----------
__global__ __launch_bounds__(256) void k_soft(const float* __restrict__ edge,
                                              const unsigned* __restrict__ maxkey,
                                              const float* __restrict__ sumE,
                                              const unsigned* __restrict__ pref1,
                                              const unsigned* __restrict__ pref2,
                                              const unsigned* __restrict__ pref3,
                                              float* __restrict__ soft,
                                              float* __restrict__ msum) {
  const int b = blockIdx.y;
  const float mx = finv(maxkey[b]);
  const float Z = sumE[b];
  const float th = load_thr(pref1, pref2, pref3, b);
  const int off = b * NSQ + blockIdx.x * 2048 + threadIdx.x * 8;
  float s = 0.f;
#pragma unroll
  for (int i = 0; i < 8; i += 4) {
    float4 v = *(const float4*)&edge[off + i];
    float4 o = make_float4(__expf((v.x - mx) * 2.f) / Z, __expf((v.y - mx) * 2.f) / Z,
                           __expf((v.z - mx) * 2.f) / Z, __expf((v.w - mx) * 2.f) / Z);
    *(float4*)&soft[off + i] = o;
    if (v.x >= th) s += o.x;
    if (v.y >= th) s += o.y;
    if (v.z >= th) s += o.z;
    if (v.w >= th) s += o.w;
  }
  __shared__ float wm[4];
  s = blockReduceSum(s, wm);
  if (threadIdx.x == 0) atomicAdd(&msum[b], s);
}

// ---------- final: causal/conf from edge (recompute soft -> consistent) ----------
__global__ __launch_bounds__(256) void k_final(const float* __restrict__ edge,
                                               const unsigned* __restrict__ maxkey,
                                               const float* __restrict__ sumE,
                                               const unsigned* __restrict__ pref1,
                                               const unsigned* __restrict__ pref2,
                                               const unsigned* __restrict__ pref3,
                                               const float* __restrict__ msum,
                                               float* __restrict__ causal,
                                               float* __restrict__ conf) {
  const int b = blockIdx.y;
  const float mx = finv(maxkey[b]);
  const float Z = sumE[b];
  const float th = load_thr(pref1, pref2, pref3, b);
  const float denom = msum[b] + 1e-12f;
  const int off = b * NSQ + blockIdx.x * 2048 + threadIdx.x * 8;
#pragma unroll
  for (int i = 0; i < 8; i += 4) {
    float4 v = *(const float4*)&edge[off + i];
    float cx = v.x >= th ? (__expf((v.x - mx) * 2.f) / Z) / denom : 0.f;
    float cy = v.y >= th ? (__expf((v.y - mx) * 2.f) / Z) / denom : 0.f;
    float cz = v.z >= th ? (__expf((v.z - mx) * 2.f) / Z) / denom : 0.f;
    float cw = v.w >= th ? (__expf((v.w - mx) * 2.f) / Z) / denom : 0.f;
    *(float4*)&causal[off + i] = make_float4(cx, cy, cz, cw);
    *(float4*)&conf[off + i]   = make_float4(1.f - cx, 1.f - cy, 1.f - cz, 1.f - cw);
  }
}

extern "C" void kernel_launch(void* const* d_in, const int* in_sizes, int n_in,
                              void* d_out, int out_size, void* d_ws, size_t ws_size,
                              hipStream_t stream) {
  const float* x  = (const float*)d_in[0];
  const float* W1 = (const float*)d_in[1];
  const float* b1 = (const float*)d_in[2];
  const float* W2 = (const float*)d_in[3];
  const float* b2 = (const float*)d_in[4];

  float* out = (float*)d_out;
  float* causal = out;
  float* conf   = out + 1 * 524288;
  float* edge   = out + 2 * 524288;
  float* soft   = out + 3 * 524288;

  float* ws = (float*)d_ws;
  float*    PRB   = ws;                          // 524288 floats
  float*    PC    = ws + 524288;                 // 524288 floats
  unsigned* base  = (unsigned*)(ws + 1048576);
  unsigned* hist1 = base;                        // 8*4096
  unsigned* hist2 = base + 32768;                // 8*4096
  unsigned* hist3 = base + 65536;                // 8*256
  unsigned* maxkey= base + 67584;                // 8
  float*    sumE  = (float*)(base + 67592);      // 8
  unsigned* pref1 = base + 67600;                // 8
  int*      kk2   = (int*)(base + 67608);        // 8
  unsigned* pref2 = base + 67616;                // 8
  int*      kk3   = (int*)(base + 67624);        // 8
  unsigned* pref3 = base + 67632;                // 8
  int*      kd    = (int*)(base + 67640);        // 8
  float*    msum  = (float*)(base + 67648);      // 8  -> NZERO = 67656

  k_init<<<(NZERO + 255) / 256, 256, 0, stream>>>(base);
  k_gemm<<<dim3(32, 8), 256, 0, stream>>>(x, W1, b1, PRB, PC);
  k_edge<<<dim3(4, 4, 8), 256, 0, stream>>>(PRB, PC, W2, b2, edge);
  k_max<<<dim3(32, 8), 256, 0, stream>>>(edge, maxkey);
  k_expsum<<<dim3(32, 8), 256, 0, stream>>>(edge, maxkey, sumE, hist1);
  k_scan<4096><<<8, 256, 0, stream>>>(hist1, nullptr, KSEL, pref1, kk2);
  k_hist2<<<dim3(32, 8), 256, 0, stream>>>(edge, pref1, hist2);
  k_scan<4096><<<8, 256, 0, stream>>>(hist2, kk2, 0, pref2, kk3);
  k_hist3<<<dim3(32, 8), 256, 0, stream>>>(edge, pref1, pref2, hist3);
  k_scan<256><<<8, 256, 0, stream>>>(hist3, kk3, 0, pref3, kd);
  k_soft<<<dim3(32, 8), 256, 0, stream>>>(edge, maxkey, sumE, pref1, pref2, pref3, soft, msum);
  k_final<<<dim3(32, 8), 256, 0, stream>>>(edge, maxkey, sumE, pref1, pref2, pref3, msum, causal, conf);
}

// Round 5
// 135.962 us; speedup vs baseline: 2.8070x; 1.1583x over previous
//
#include <hip/hip_runtime.h>

#define BB 8
#define NN 256
#define FDIM 1024
#define HDIM 256
#define NSQ 65536            // NN*NN
#define ROWS 2048            // BB*NN
#define KSEL 39321           // int(0.6*NN*NN)

typedef short s16x8 __attribute__((ext_vector_type(8)));
typedef float f32x4 __attribute__((ext_vector_type(4)));

// ---------- helpers ----------
__device__ __forceinline__ unsigned fkey(float f) {
  unsigned u = __float_as_uint(f);
  return (u & 0x80000000u) ? ~u : (u | 0x80000000u);
}
__device__ __forceinline__ float finv(unsigned k) {
  unsigned u = (k & 0x80000000u) ? (k & 0x7fffffffu) : ~k;
  return __uint_as_float(u);
}
__device__ __forceinline__ unsigned short f2bf(float f) {   // RNE
  unsigned u = __float_as_uint(f);
  unsigned r = (u + 0x7fffu + ((u >> 16) & 1u)) >> 16;
  return (unsigned short)r;
}

// ---------- K0: zero hist1 + hist2 + scalars ----------
#define NZERO 65560
__global__ __launch_bounds__(256) void k_init(unsigned* __restrict__ z) {
  int idx = blockIdx.x * 256 + threadIdx.x;
  if (idx < NZERO) z[idx] = 0u;
}

// ---------- K1: bf16-MFMA GEMM, TRANSPOSED outputs ----------
// PRBT[h][row] = (x@Wr^T + b1)^T ; PCT[h][row] = (x@Wc^T)^T, row = b*256+n.
// Block: 64x64 tile, 256 thr = 4 waves, wave 32x32 via 2x2 mfma_16x16x32.
// K-chunk 64/iter; mfma consumes K=32 -> two MFMA groups at +0 and +32.
#define LDSW 72   // row stride in bf16 elems (64 + 8 pad); 144 B
__global__ __launch_bounds__(256) void k_gemm(const float* __restrict__ X,
                                              const float* __restrict__ W1,
                                              const float* __restrict__ b1,
                                              float* __restrict__ PRBT,
                                              float* __restrict__ PCT) {
  const int bm = blockIdx.x * 64;
  const int bn = blockIdx.y * 64;         // 0..511
  const int t = threadIdx.x;
  __shared__ short As[64 * LDSW];
  __shared__ short Bs[64 * LDSW];
  const int sr = t >> 2, cg = t & 3;      // staging: row 0..63, 16-float col group
  const float* pa = X + (bm + sr) * FDIM + cg * 16;
  const float* pb = (bn < 256) ? (W1 + (bn + sr) * (2 * FDIM) + cg * 16)
                               : (W1 + (bn - 256 + sr) * (2 * FDIM) + FDIM + cg * 16);
  const int w = t >> 6, lane = t & 63;
  const int wm = (w >> 1) * 32, wn = (w & 1) * 32;
  const int q = lane >> 4, m16 = lane & 15;
  f32x4 acc[2][2] = {};
  for (int k0 = 0; k0 < FDIM; k0 += 64) {
    float4 a0 = *(const float4*)(pa + k0);
    float4 a1 = *(const float4*)(pa + k0 + 4);
    float4 a2 = *(const float4*)(pa + k0 + 8);
    float4 a3 = *(const float4*)(pa + k0 + 12);
    float4 b0 = *(const float4*)(pb + k0);
    float4 b1v = *(const float4*)(pb + k0 + 4);
    float4 b2v = *(const float4*)(pb + k0 + 8);
    float4 b3v = *(const float4*)(pb + k0 + 12);
    s16x8 avlo, avhi, bvlo, bvhi;
    avlo[0] = (short)f2bf(a0.x); avlo[1] = (short)f2bf(a0.y); avlo[2] = (short)f2bf(a0.z); avlo[3] = (short)f2bf(a0.w);
    avlo[4] = (short)f2bf(a1.x); avlo[5] = (short)f2bf(a1.y); avlo[6] = (short)f2bf(a1.z); avlo[7] = (short)f2bf(a1.w);
    avhi[0] = (short)f2bf(a2.x); avhi[1] = (short)f2bf(a2.y); avhi[2] = (short)f2bf(a2.z); avhi[3] = (short)f2bf(a2.w);
    avhi[4] = (short)f2bf(a3.x); avhi[5] = (short)f2bf(a3.y); avhi[6] = (short)f2bf(a3.z); avhi[7] = (short)f2bf(a3.w);
    bvlo[0] = (short)f2bf(b0.x); bvlo[1] = (short)f2bf(b0.y); bvlo[2] = (short)f2bf(b0.z); bvlo[3] = (short)f2bf(b0.w);
    bvlo[4] = (short)f2bf(b1v.x); bvlo[5] = (short)f2bf(b1v.y); bvlo[6] = (short)f2bf(b1v.z); bvlo[7] = (short)f2bf(b1v.w);
    bvhi[0] = (short)f2bf(b2v.x); bvhi[1] = (short)f2bf(b2v.y); bvhi[2] = (short)f2bf(b2v.z); bvhi[3] = (short)f2bf(b2v.w);
    bvhi[4] = (short)f2bf(b3v.x); bvhi[5] = (short)f2bf(b3v.y); bvhi[6] = (short)f2bf(b3v.z); bvhi[7] = (short)f2bf(b3v.w);
    __syncthreads();
    *(s16x8*)&As[sr * LDSW + cg * 16]     = avlo;
    *(s16x8*)&As[sr * LDSW + cg * 16 + 8] = avhi;
    *(s16x8*)&Bs[sr * LDSW + cg * 16]     = bvlo;
    *(s16x8*)&Bs[sr * LDSW + cg * 16 + 8] = bvhi;
    __syncthreads();
    {
      s16x8 af0 = *(s16x8*)&As[(wm + m16) * LDSW + q * 8];
      s16x8 af1 = *(s16x8*)&As[(wm + 16 + m16) * LDSW + q * 8];
      s16x8 bf0 = *(s16x8*)&Bs[(wn + m16) * LDSW + q * 8];
      s16x8 bf1 = *(s16x8*)&Bs[(wn + 16 + m16) * LDSW + q * 8];
      acc[0][0] = __builtin_amdgcn_mfma_f32_16x16x32_bf16(af0, bf0, acc[0][0], 0, 0, 0);
      acc[0][1] = __builtin_amdgcn_mfma_f32_16x16x32_bf16(af0, bf1, acc[0][1], 0, 0, 0);
      acc[1][0] = __builtin_amdgcn_mfma_f32_16x16x32_bf16(af1, bf0, acc[1][0], 0, 0, 0);
      acc[1][1] = __builtin_amdgcn_mfma_f32_16x16x32_bf16(af1, bf1, acc[1][1], 0, 0, 0);
    }
    {
      s16x8 af0 = *(s16x8*)&As[(wm + m16) * LDSW + 32 + q * 8];
      s16x8 af1 = *(s16x8*)&As[(wm + 16 + m16) * LDSW + 32 + q * 8];
      s16x8 bf0 = *(s16x8*)&Bs[(wn + m16) * LDSW + 32 + q * 8];
      s16x8 bf1 = *(s16x8*)&Bs[(wn + 16 + m16) * LDSW + 32 + q * 8];
      acc[0][0] = __builtin_amdgcn_mfma_f32_16x16x32_bf16(af0, bf0, acc[0][0], 0, 0, 0);
      acc[0][1] = __builtin_amdgcn_mfma_f32_16x16x32_bf16(af0, bf1, acc[0][1], 0, 0, 0);
      acc[1][0] = __builtin_amdgcn_mfma_f32_16x16x32_bf16(af1, bf0, acc[1][0], 0, 0, 0);
      acc[1][1] = __builtin_amdgcn_mfma_f32_16x16x32_bf16(af1, bf1, acc[1][1], 0, 0, 0);
    }
  }
  // epilogue: D lane map col(hn)=lane&15, row=(lane>>4)*4+reg.
  // Transposed store: rows are contiguous -> one b128 per (rt,ct).
#pragma unroll
  for (int rt = 0; rt < 2; ++rt) {
#pragma unroll
    for (int ct = 0; ct < 2; ++ct) {
      const int hn = bn + wn + ct * 16 + m16;       // 0..511
      const int row0 = bm + wm + rt * 16 + q * 4;
      if (hn < 256) {
        const float bias = b1[hn];
        float4 v = make_float4(acc[rt][ct][0] + bias, acc[rt][ct][1] + bias,
                               acc[rt][ct][2] + bias, acc[rt][ct][3] + bias);
        *(float4*)&PRBT[hn * ROWS + row0] = v;
      } else {
        float4 v = make_float4(acc[rt][ct][0], acc[rt][ct][1],
                               acc[rt][ct][2], acc[rt][ct][3]);
        *(float4*)&PCT[(hn - 256) * ROWS + row0] = v;
      }
    }
  }
}

// ---------- K2: edge + fused expsum + fused level-1 histogram ----------
// edge[b,i,j] = sum_h relu(PRBT[h,b*256+i] + PCT[h,b*256+j]) * W2[h] + b2
// tile 64(i) x 32(j), 128 threads, 4x4 per thread; grid (8,4,8) = 256 blocks.
__global__ __launch_bounds__(128) void k_edge(const float* __restrict__ PRBT,
                                              const float* __restrict__ PCT,
                                              const float* __restrict__ W2,
                                              const float* __restrict__ b2,
                                              float* __restrict__ edge,
                                              float* __restrict__ sumE,
                                              unsigned* __restrict__ hist1) {
  const int b = blockIdx.z;
  const int i0 = blockIdx.y * 64, j0 = blockIdx.x * 32;
  const int t = threadIdx.x;
  __shared__ float prs[64][68];   // [h][i]
  __shared__ float pcs[64][36];   // [h][j]
  __shared__ float w2s[HDIM];
  __shared__ unsigned lh[4096];
  __shared__ float wm[2];
  w2s[t] = W2[t]; w2s[t + 128] = W2[t + 128];
#pragma unroll
  for (int i = 0; i < 32; ++i) lh[t + i * 128] = 0u;
  const float bias = b2[0];
  const int tmi = t >> 3, tnj = t & 7;
  float acc[4][4] = {};
  for (int h0 = 0; h0 < HDIM; h0 += 64) {
    __syncthreads();
    // stage prs: 64h x 64i (b128 writes, contiguous in i)
#pragma unroll
    for (int it = 0; it < 8; ++it) {
      int hh = it * 8 + (t >> 4);
      int ig = t & 15;
      float4 v = *(const float4*)&PRBT[(h0 + hh) * ROWS + b * NN + i0 + ig * 4];
      *(float4*)&prs[hh][ig * 4] = v;
    }
    // stage pcs: 64h x 32j
#pragma unroll
    for (int it = 0; it < 4; ++it) {
      int hh = it * 16 + (t >> 3);
      int jg = t & 7;
      float4 v = *(const float4*)&PCT[(h0 + hh) * ROWS + b * NN + j0 + jg * 4];
      *(float4*)&pcs[hh][jg * 4] = v;
    }
    __syncthreads();
#pragma unroll 4
    for (int h = 0; h < 64; ++h) {
      const float w = w2s[h0 + h];
      const float4 a = *(const float4*)&prs[h][tmi * 4];
      const float4 c = *(const float4*)&pcs[h][tnj * 4];
      const float ai[4] = {a.x, a.y, a.z, a.w};
      const float cj[4] = {c.x, c.y, c.z, c.w};
#pragma unroll
      for (int i = 0; i < 4; ++i)
#pragma unroll
        for (int j = 0; j < 4; ++j)
          acc[i][j] += fmaxf(ai[i] + cj[j], 0.f) * w;
    }
  }
  // write edge + exp-sum + hist1 (values in registers)
  float s = 0.f;
  const int ibase = i0 + tmi * 4, jbase = j0 + tnj * 4;
#pragma unroll
  for (int i = 0; i < 4; ++i) {
    float4 v = make_float4(acc[i][0] + bias, acc[i][1] + bias,
                           acc[i][2] + bias, acc[i][3] + bias);
    *(float4*)&edge[b * NSQ + (ibase + i) * NN + jbase] = v;
    s += __expf(v.x * 2.f) + __expf(v.y * 2.f) + __expf(v.z * 2.f) + __expf(v.w * 2.f);
    atomicAdd(&lh[fkey(v.x) >> 20], 1u);
    atomicAdd(&lh[fkey(v.y) >> 20], 1u);
    atomicAdd(&lh[fkey(v.z) >> 20], 1u);
    atomicAdd(&lh[fkey(v.w) >> 20], 1u);
  }
  for (int off = 32; off > 0; off >>= 1) s += __shfl_down(s, off);
  if ((t & 63) == 0) wm[t >> 6] = s;
  __syncthreads();   // also ensures all lh atomics complete
  if (t == 0) atomicAdd(&sumE[b], wm[0] + wm[1]);
  unsigned* g = hist1 + b * 4096;
#pragma unroll
  for (int i = 0; i < 32; ++i) {
    unsigned c = lh[t + i * 128];
    if (c) atomicAdd(&g[t + i * 128], c);
  }
}

// ---------- inline scan: bin of k-th largest (descending) over NB bins ----------
template<int NB>
__device__ __forceinline__ void scan_find(const unsigned* __restrict__ h, int k,
                                          unsigned* S, unsigned* o2,
                                          unsigned& pref, int& kres) {
  constexpr int C = NB / 256;
  const int t = threadIdx.x;
  unsigned loc[C];
  unsigned cs = 0;
#pragma unroll
  for (int i = 0; i < C; ++i) { loc[i] = h[t * C + i]; cs += loc[i]; }
  S[t] = cs;
  __syncthreads();
  for (int off = 1; off < 256; off <<= 1) {   // inclusive suffix sum
    unsigned u = (t + off < 256) ? S[t + off] : 0u;
    __syncthreads();
    S[t] += u;
    __syncthreads();
  }
  const int above = (int)(S[t] - cs);
  if (above < k && (int)S[t] >= k) {          // exactly one thread
    int cum = above;
    for (int i = C - 1; i >= 0; --i) {
      cum += (int)loc[i];
      if (cum >= k) {
        o2[0] = (unsigned)(t * C + i);
        o2[1] = (unsigned)(k - (cum - (int)loc[i]));
        break;
      }
    }
  }
  __syncthreads();
  pref = o2[0]; kres = (int)o2[1];
  __syncthreads();   // safe S/o2 reuse
}

// ---------- K3: level-2 histogram (bits 8..19), scan1 inlined ----------
__global__ __launch_bounds__(256) void k_hist2(const float* __restrict__ edge,
                                               const unsigned* __restrict__ hist1,
                                               unsigned* __restrict__ hist2) {
  const int b = blockIdx.y;
  const int t = threadIdx.x;
  __shared__ unsigned S[256];
  __shared__ unsigned o2[2];
  __shared__ unsigned lh[4096];
#pragma unroll
  for (int i = 0; i < 16; ++i) lh[t + i * 256] = 0u;
  unsigned p1; int k2;
  scan_find<4096>(hist1 + b * 4096, KSEL, S, o2, p1, k2);
  const float* p = edge + b * NSQ + blockIdx.x * 2048 + t * 8;
#pragma unroll
  for (int i = 0; i < 8; i += 4) {
    float4 v = *(const float4*)&p[i];
    unsigned kx = fkey(v.x), ky = fkey(v.y), kz = fkey(v.z), kw = fkey(v.w);
    if ((kx >> 20) == p1) atomicAdd(&lh[(kx >> 8) & 0xFFFu], 1u);
    if ((ky >> 20) == p1) atomicAdd(&lh[(ky >> 8) & 0xFFFu], 1u);
    if ((kz >> 20) == p1) atomicAdd(&lh[(kz >> 8) & 0xFFFu], 1u);
    if ((kw >> 20) == p1) atomicAdd(&lh[(kw >> 8) & 0xFFFu], 1u);
  }
  __syncthreads();
  unsigned* g = hist2 + b * 4096;
#pragma unroll
  for (int i = 0; i < 16; ++i) {
    unsigned c = lh[t + i * 256];
    if (c) atomicAdd(&g[t + i * 256], c);
  }
}

__device__ __forceinline__ float blockReduceSum256(float v, float* wm) {
  for (int off = 32; off > 0; off >>= 1) v += __shfl_down(v, off);
  int lane = threadIdx.x & 63, wid = threadIdx.x >> 6;
  if (lane == 0) wm[wid] = v;
  __syncthreads();
  return wm[0] + wm[1] + wm[2] + wm[3];
}

// ---------- K4: soft write + masked sum; scans 1+2 inlined; th -> global ----------
__global__ __launch_bounds__(256) void k_soft(const float* __restrict__ edge,
                                              const float* __restrict__ sumE,
                                              const unsigned* __restrict__ hist1,
                                              const unsigned* __restrict__ hist2,
                                              float* __restrict__ soft,
                                              float* __restrict__ msum,
                                              float* __restrict__ thg) {
  const int b = blockIdx.y;
  const int t = threadIdx.x;
  __shared__ unsigned S[256];
  __shared__ unsigned o2[2];
  __shared__ float wm[4];
  unsigned p1, p2; int k2, k3;
  scan_find<4096>(hist1 + b * 4096, KSEL, S, o2, p1, k2);
  scan_find<4096>(hist2 + b * 4096, k2, S, o2, p2, k3);
  const float th = finv((p1 << 20) | (p2 << 8));   // 24-bit truncated threshold
  if (blockIdx.x == 0 && t == 0) thg[b] = th;
  const float Z = sumE[b];
  const int off = b * NSQ + blockIdx.x * 2048 + t * 8;
  float s = 0.f;
#pragma unroll
  for (int i = 0; i < 8; i += 4) {
    float4 v = *(const float4*)&edge[off + i];
    float4 o = make_float4(__expf(v.x * 2.f) / Z, __expf(v.y * 2.f) / Z,
                           __expf(v.z * 2.f) / Z, __expf(v.w * 2.f) / Z);
    *(float4*)&soft[off + i] = o;
    if (v.x >= th) s += o.x;
    if (v.y >= th) s += o.y;
    if (v.z >= th) s += o.z;
    if (v.w >= th) s += o.w;
  }
  s = blockReduceSum256(s, wm);
  if (t == 0) atomicAdd(&msum[b], s);
}

// ---------- K5: final causal/conf (recompute soft from edge -> bit-identical) ----------
__global__ __launch_bounds__(256) void k_final(const float* __restrict__ edge,
                                               const float* __restrict__ sumE,
                                               const float* __restrict__ thg,
                                               const float* __restrict__ msum,
                                               float* __restrict__ causal,
                                               float* __restrict__ conf) {
  const int b = blockIdx.y;
  const float th = thg[b];
  const float Z = sumE[b];
  const float denom = msum[b] + 1e-12f;
  const int off = b * NSQ + blockIdx.x * 2048 + threadIdx.x * 8;
#pragma unroll
  for (int i = 0; i < 8; i += 4) {
    float4 v = *(const float4*)&edge[off + i];
    float cx = v.x >= th ? (__expf(v.x * 2.f) / Z) / denom : 0.f;
    float cy = v.y >= th ? (__expf(v.y * 2.f) / Z) / denom : 0.f;
    float cz = v.z >= th ? (__expf(v.z * 2.f) / Z) / denom : 0.f;
    float cw = v.w >= th ? (__expf(v.w * 2.f) / Z) / denom : 0.f;
    *(float4*)&causal[off + i] = make_float4(cx, cy, cz, cw);
    *(float4*)&conf[off + i]   = make_float4(1.f - cx, 1.f - cy, 1.f - cz, 1.f - cw);
  }
}

extern "C" void kernel_launch(void* const* d_in, const int* in_sizes, int n_in,
                              void* d_out, int out_size, void* d_ws, size_t ws_size,
                              hipStream_t stream) {
  const float* x  = (const float*)d_in[0];
  const float* W1 = (const float*)d_in[1];
  const float* b1 = (const float*)d_in[2];
  const float* W2 = (const float*)d_in[3];
  const float* b2 = (const float*)d_in[4];

  float* out = (float*)d_out;
  float* causal = out;
  float* conf   = out + 1 * 524288;
  float* edge   = out + 2 * 524288;
  float* soft   = out + 3 * 524288;

  float* ws = (float*)d_ws;
  float*    PRBT  = ws;                          // 524288 floats [h][row]
  float*    PCT   = ws + 524288;                 // 524288 floats [h][row]
  unsigned* base  = (unsigned*)(ws + 1048576);
  unsigned* hist1 = base;                        // 8*4096
  unsigned* hist2 = base + 32768;                // 8*4096
  float*    sumE  = (float*)(base + 65536);      // 8
  float*    msum  = (float*)(base + 65544);      // 8
  float*    thg   = (float*)(base + 65552);      // 8  -> NZERO = 65560

  k_init<<<(NZERO + 255) / 256, 256, 0, stream>>>(base);
  k_gemm<<<dim3(32, 8), 256, 0, stream>>>(x, W1, b1, PRBT, PCT);
  k_edge<<<dim3(8, 4, 8), 128, 0, stream>>>(PRBT, PCT, W2, b2, edge, sumE, hist1);
  k_hist2<<<dim3(32, 8), 256, 0, stream>>>(edge, hist1, hist2);
  k_soft<<<dim3(32, 8), 256, 0, stream>>>(edge, sumE, hist1, hist2, soft, msum, thg);
  k_final<<<dim3(32, 8), 256, 0, stream>>>(edge, sumE, thg, msum, causal, conf);
}

// Round 6
// 126.519 us; speedup vs baseline: 3.0165x; 1.0746x over previous
//
#include <hip/hip_runtime.h>

#define BB 8
#define NN 256
#define FDIM 1024
#define HDIM 256
#define NSQ 65536            // NN*NN
#define ROWS 2048            // BB*NN
#define KSEL 39321           // int(0.6*NN*NN)

typedef short s16x8 __attribute__((ext_vector_type(8)));
typedef float f32x4 __attribute__((ext_vector_type(4)));

// ---------- helpers ----------
__device__ __forceinline__ unsigned fkey(float f) {
  unsigned u = __float_as_uint(f);
  return (u & 0x80000000u) ? ~u : (u | 0x80000000u);
}
__device__ __forceinline__ float finv(unsigned k) {
  unsigned u = (k & 0x80000000u) ? (k & 0x7fffffffu) : ~k;
  return __uint_as_float(u);
}
__device__ __forceinline__ unsigned short f2bf(float f) {   // RNE
  unsigned u = __float_as_uint(f);
  unsigned r = (u + 0x7fffu + ((u >> 16) & 1u)) >> 16;
  return (unsigned short)r;
}

// ---------- K0: zero hist1/vsum1/hist2/vsum2 + sumE ----------
#define NZERO 131080
__global__ __launch_bounds__(256) void k_init(unsigned* __restrict__ z) {
  int idx = blockIdx.x * 256 + threadIdx.x;
  if (idx < NZERO) z[idx] = 0u;
}

// ---------- K1: bf16-MFMA GEMM, TRANSPOSED outputs ----------
// PRBT[h][row] = (x@Wr^T + b1)^T ; PCT[h][row] = (x@Wc^T)^T, row = b*256+n.
#define LDSW 72   // row stride in bf16 elems (64 + 8 pad); 144 B
__global__ __launch_bounds__(256) void k_gemm(const float* __restrict__ X,
                                              const float* __restrict__ W1,
                                              const float* __restrict__ b1,
                                              float* __restrict__ PRBT,
                                              float* __restrict__ PCT) {
  const int bm = blockIdx.x * 64;
  const int bn = blockIdx.y * 64;         // 0..511
  const int t = threadIdx.x;
  __shared__ short As[64 * LDSW];
  __shared__ short Bs[64 * LDSW];
  const int sr = t >> 2, cg = t & 3;      // staging: row 0..63, 16-float col group
  const float* pa = X + (bm + sr) * FDIM + cg * 16;
  const float* pb = (bn < 256) ? (W1 + (bn + sr) * (2 * FDIM) + cg * 16)
                               : (W1 + (bn - 256 + sr) * (2 * FDIM) + FDIM + cg * 16);
  const int w = t >> 6, lane = t & 63;
  const int wm = (w >> 1) * 32, wn = (w & 1) * 32;
  const int q = lane >> 4, m16 = lane & 15;
  f32x4 acc[2][2] = {};
  for (int k0 = 0; k0 < FDIM; k0 += 64) {
    float4 a0 = *(const float4*)(pa + k0);
    float4 a1 = *(const float4*)(pa + k0 + 4);
    float4 a2 = *(const float4*)(pa + k0 + 8);
    float4 a3 = *(const float4*)(pa + k0 + 12);
    float4 b0 = *(const float4*)(pb + k0);
    float4 b1v = *(const float4*)(pb + k0 + 4);
    float4 b2v = *(const float4*)(pb + k0 + 8);
    float4 b3v = *(const float4*)(pb + k0 + 12);
    s16x8 avlo, avhi, bvlo, bvhi;
    avlo[0] = (short)f2bf(a0.x); avlo[1] = (short)f2bf(a0.y); avlo[2] = (short)f2bf(a0.z); avlo[3] = (short)f2bf(a0.w);
    avlo[4] = (short)f2bf(a1.x); avlo[5] = (short)f2bf(a1.y); avlo[6] = (short)f2bf(a1.z); avlo[7] = (short)f2bf(a1.w);
    avhi[0] = (short)f2bf(a2.x); avhi[1] = (short)f2bf(a2.y); avhi[2] = (short)f2bf(a2.z); avhi[3] = (short)f2bf(a2.w);
    avhi[4] = (short)f2bf(a3.x); avhi[5] = (short)f2bf(a3.y); avhi[6] = (short)f2bf(a3.z); avhi[7] = (short)f2bf(a3.w);
    bvlo[0] = (short)f2bf(b0.x); bvlo[1] = (short)f2bf(b0.y); bvlo[2] = (short)f2bf(b0.z); bvlo[3] = (short)f2bf(b0.w);
    bvlo[4] = (short)f2bf(b1v.x); bvlo[5] = (short)f2bf(b1v.y); bvlo[6] = (short)f2bf(b1v.z); bvlo[7] = (short)f2bf(b1v.w);
    bvhi[0] = (short)f2bf(b2v.x); bvhi[1] = (short)f2bf(b2v.y); bvhi[2] = (short)f2bf(b2v.z); bvhi[3] = (short)f2bf(b2v.w);
    bvhi[4] = (short)f2bf(b3v.x); bvhi[5] = (short)f2bf(b3v.y); bvhi[6] = (short)f2bf(b3v.z); bvhi[7] = (short)f2bf(b3v.w);
    __syncthreads();
    *(s16x8*)&As[sr * LDSW + cg * 16]     = avlo;
    *(s16x8*)&As[sr * LDSW + cg * 16 + 8] = avhi;
    *(s16x8*)&Bs[sr * LDSW + cg * 16]     = bvlo;
    *(s16x8*)&Bs[sr * LDSW + cg * 16 + 8] = bvhi;
    __syncthreads();
    {
      s16x8 af0 = *(s16x8*)&As[(wm + m16) * LDSW + q * 8];
      s16x8 af1 = *(s16x8*)&As[(wm + 16 + m16) * LDSW + q * 8];
      s16x8 bf0 = *(s16x8*)&Bs[(wn + m16) * LDSW + q * 8];
      s16x8 bf1 = *(s16x8*)&Bs[(wn + 16 + m16) * LDSW + q * 8];
      acc[0][0] = __builtin_amdgcn_mfma_f32_16x16x32_bf16(af0, bf0, acc[0][0], 0, 0, 0);
      acc[0][1] = __builtin_amdgcn_mfma_f32_16x16x32_bf16(af0, bf1, acc[0][1], 0, 0, 0);
      acc[1][0] = __builtin_amdgcn_mfma_f32_16x16x32_bf16(af1, bf0, acc[1][0], 0, 0, 0);
      acc[1][1] = __builtin_amdgcn_mfma_f32_16x16x32_bf16(af1, bf1, acc[1][1], 0, 0, 0);
    }
    {
      s16x8 af0 = *(s16x8*)&As[(wm + m16) * LDSW + 32 + q * 8];
      s16x8 af1 = *(s16x8*)&As[(wm + 16 + m16) * LDSW + 32 + q * 8];
      s16x8 bf0 = *(s16x8*)&Bs[(wn + m16) * LDSW + 32 + q * 8];
      s16x8 bf1 = *(s16x8*)&Bs[(wn + 16 + m16) * LDSW + 32 + q * 8];
      acc[0][0] = __builtin_amdgcn_mfma_f32_16x16x32_bf16(af0, bf0, acc[0][0], 0, 0, 0);
      acc[0][1] = __builtin_amdgcn_mfma_f32_16x16x32_bf16(af0, bf1, acc[0][1], 0, 0, 0);
      acc[1][0] = __builtin_amdgcn_mfma_f32_16x16x32_bf16(af1, bf0, acc[1][0], 0, 0, 0);
      acc[1][1] = __builtin_amdgcn_mfma_f32_16x16x32_bf16(af1, bf1, acc[1][1], 0, 0, 0);
    }
  }
#pragma unroll
  for (int rt = 0; rt < 2; ++rt) {
#pragma unroll
    for (int ct = 0; ct < 2; ++ct) {
      const int hn = bn + wn + ct * 16 + m16;       // 0..511
      const int row0 = bm + wm + rt * 16 + q * 4;
      if (hn < 256) {
        const float bias = b1[hn];
        float4 v = make_float4(acc[rt][ct][0] + bias, acc[rt][ct][1] + bias,
                               acc[rt][ct][2] + bias, acc[rt][ct][3] + bias);
        *(float4*)&PRBT[hn * ROWS + row0] = v;
      } else {
        float4 v = make_float4(acc[rt][ct][0], acc[rt][ct][1],
                               acc[rt][ct][2], acc[rt][ct][3]);
        *(float4*)&PCT[(hn - 256) * ROWS + row0] = v;
      }
    }
  }
}

// ---------- K2: edge + fused expsum + level-1 count/value histograms ----------
// tile 64(i) x 32(j), 256 threads (4 waves -> all 4 SIMDs), 4x2 per thread.
__global__ __launch_bounds__(256) void k_edge(const float* __restrict__ PRBT,
                                              const float* __restrict__ PCT,
                                              const float* __restrict__ W2,
                                              const float* __restrict__ b2,
                                              float* __restrict__ edge,
                                              float* __restrict__ sumE,
                                              unsigned* __restrict__ hist1,
                                              float* __restrict__ vsum1) {
  const int b = blockIdx.z;
  const int i0 = blockIdx.y * 64, j0 = blockIdx.x * 32;
  const int t = threadIdx.x;
  __shared__ float prs[64][68];   // [h][i]
  __shared__ float pcs[64][36];   // [h][j]
  __shared__ float w2s[HDIM];
  __shared__ unsigned lh[4096];
  __shared__ float lhv[4096];
  __shared__ float wm[4];
  w2s[t] = W2[t];
#pragma unroll
  for (int i = 0; i < 16; ++i) { lh[t + i * 256] = 0u; lhv[t + i * 256] = 0.f; }
  const float bias = b2[0];
  const int tmi = t >> 4, tnj = t & 15;     // i-group 0..15 (x4), j-group 0..15 (x2)
  float acc[4][2] = {};
  for (int h0 = 0; h0 < HDIM; h0 += 64) {
    __syncthreads();
#pragma unroll
    for (int it = 0; it < 4; ++it) {        // prs: 64h x 64i
      int hh = it * 16 + (t >> 4);
      int ig = t & 15;
      *(float4*)&prs[hh][ig * 4] =
          *(const float4*)&PRBT[(h0 + hh) * ROWS + b * NN + i0 + ig * 4];
    }
#pragma unroll
    for (int it = 0; it < 2; ++it) {        // pcs: 64h x 32j
      int hh = it * 32 + (t >> 3);
      int jg = t & 7;
      *(float4*)&pcs[hh][jg * 4] =
          *(const float4*)&PCT[(h0 + hh) * ROWS + b * NN + j0 + jg * 4];
    }
    __syncthreads();
#pragma unroll 8
    for (int h = 0; h < 64; ++h) {
      const float w = w2s[h0 + h];
      const float4 a = *(const float4*)&prs[h][tmi * 4];
      const float2 c = *(const float2*)&pcs[h][tnj * 2];
      const float ai[4] = {a.x, a.y, a.z, a.w};
#pragma unroll
      for (int i = 0; i < 4; ++i) {
        acc[i][0] += fmaxf(ai[i] + c.x, 0.f) * w;
        acc[i][1] += fmaxf(ai[i] + c.y, 0.f) * w;
      }
    }
  }
  // write edge + exp-sum + hist1/vsum1 (values in registers)
  float s = 0.f;
  const int ibase = i0 + tmi * 4, jbase = j0 + tnj * 2;
#pragma unroll
  for (int i = 0; i < 4; ++i) {
    float2 v = make_float2(acc[i][0] + bias, acc[i][1] + bias);
    *(float2*)&edge[b * NSQ + (ibase + i) * NN + jbase] = v;
    float ex = __expf(v.x * 2.f), ey = __expf(v.y * 2.f);
    s += ex + ey;
    unsigned bx = fkey(v.x) >> 20, by = fkey(v.y) >> 20;
    atomicAdd(&lh[bx], 1u);  atomicAdd(&lhv[bx], ex);
    atomicAdd(&lh[by], 1u);  atomicAdd(&lhv[by], ey);
  }
  for (int off = 32; off > 0; off >>= 1) s += __shfl_down(s, off);
  if ((t & 63) == 0) wm[t >> 6] = s;
  __syncthreads();   // also ensures all lh/lhv atomics complete
  if (t == 0) atomicAdd(&sumE[b], wm[0] + wm[1] + wm[2] + wm[3]);
  unsigned* g = hist1 + b * 4096;
  float* gv = vsum1 + b * 4096;
#pragma unroll
  for (int i = 0; i < 16; ++i) {
    unsigned c = lh[t + i * 256];
    if (c) { atomicAdd(&g[t + i * 256], c); atomicAdd(&gv[t + i * 256], lhv[t + i * 256]); }
  }
}

// ---------- inline paired scan: bin of k-th largest + value suffixes ----------
// Returns: bin index, residual k, vabove = value-sum strictly above bin,
// vbin = value-sum of the bin itself.
__device__ __forceinline__ void scan_pair(const unsigned* __restrict__ hc,
                                          const float* __restrict__ hv, int k,
                                          unsigned* S, float* V,
                                          unsigned* ou, float* of,
                                          unsigned& bin, int& kres,
                                          float& vabove, float& vbin) {
  const int t = threadIdx.x;
  unsigned loc[16]; float locv[16];
  unsigned cs = 0; float vs = 0.f;
#pragma unroll
  for (int i = 0; i < 16; ++i) {
    loc[i] = hc[t * 16 + i]; cs += loc[i];
    locv[i] = hv[t * 16 + i]; vs += locv[i];
  }
  S[t] = cs; V[t] = vs;
  __syncthreads();
  for (int off = 1; off < 256; off <<= 1) {   // inclusive suffix sums
    unsigned su = (t + off < 256) ? S[t + off] : 0u;
    float vu = (t + off < 256) ? V[t + off] : 0.f;
    __syncthreads();
    S[t] += su; V[t] += vu;
    __syncthreads();
  }
  const int above = (int)(S[t] - cs);
  if (above < k && (int)S[t] >= k) {          // exactly one thread
    int cum = above;
    float vcum = V[t] - vs;
    for (int i = 15; i >= 0; --i) {
      cum += (int)loc[i];
      if (cum >= k) {
        ou[0] = (unsigned)(t * 16 + i);
        ou[1] = (unsigned)(k - (cum - (int)loc[i]));
        of[0] = vcum;
        of[1] = locv[i];
        break;
      }
      vcum += locv[i];
    }
  }
  __syncthreads();
  bin = ou[0]; kres = (int)ou[1]; vabove = of[0]; vbin = of[1];
  __syncthreads();   // safe S/V/ou/of reuse
}

// ---------- K3: level-2 count/value histogram (bits 8..19), scan1 inlined ----------
__global__ __launch_bounds__(256) void k_hist2(const float* __restrict__ edge,
                                               const unsigned* __restrict__ hist1,
                                               const float* __restrict__ vsum1,
                                               unsigned* __restrict__ hist2,
                                               float* __restrict__ vsum2) {
  const int b = blockIdx.y;
  const int t = threadIdx.x;
  __shared__ unsigned S[256];
  __shared__ float V[256];
  __shared__ unsigned ou[2];
  __shared__ float of[2];
  __shared__ unsigned lh[4096];
  __shared__ float lhv[4096];
#pragma unroll
  for (int i = 0; i < 16; ++i) { lh[t + i * 256] = 0u; lhv[t + i * 256] = 0.f; }
  unsigned p1; int k2; float va, vb;
  scan_pair(hist1 + b * 4096, vsum1 + b * 4096, KSEL, S, V, ou, of, p1, k2, va, vb);
  const float* p = edge + b * NSQ + blockIdx.x * 2048 + t * 8;
#pragma unroll
  for (int i = 0; i < 8; i += 4) {
    float4 v = *(const float4*)&p[i];
    unsigned kx = fkey(v.x), ky = fkey(v.y), kz = fkey(v.z), kw = fkey(v.w);
    if ((kx >> 20) == p1) { atomicAdd(&lh[(kx >> 8) & 0xFFFu], 1u); atomicAdd(&lhv[(kx >> 8) & 0xFFFu], __expf(v.x * 2.f)); }
    if ((ky >> 20) == p1) { atomicAdd(&lh[(ky >> 8) & 0xFFFu], 1u); atomicAdd(&lhv[(ky >> 8) & 0xFFFu], __expf(v.y * 2.f)); }
    if ((kz >> 20) == p1) { atomicAdd(&lh[(kz >> 8) & 0xFFFu], 1u); atomicAdd(&lhv[(kz >> 8) & 0xFFFu], __expf(v.z * 2.f)); }
    if ((kw >> 20) == p1) { atomicAdd(&lh[(kw >> 8) & 0xFFFu], 1u); atomicAdd(&lhv[(kw >> 8) & 0xFFFu], __expf(v.w * 2.f)); }
  }
  __syncthreads();
  unsigned* g = hist2 + b * 4096;
  float* gv = vsum2 + b * 4096;
#pragma unroll
  for (int i = 0; i < 16; ++i) {
    unsigned c = lh[t + i * 256];
    if (c) { atomicAdd(&g[t + i * 256], c); atomicAdd(&gv[t + i * 256], lhv[t + i * 256]); }
  }
}

// ---------- K4: merged soft + causal + conf ----------
// th and msum derived from histograms via inline scans (no extra passes).
__global__ __launch_bounds__(256) void k_out(const float* __restrict__ edge,
                                             const float* __restrict__ sumE,
                                             const unsigned* __restrict__ hist1,
                                             const float* __restrict__ vsum1,
                                             const unsigned* __restrict__ hist2,
                                             const float* __restrict__ vsum2,
                                             float* __restrict__ soft,
                                             float* __restrict__ causal,
                                             float* __restrict__ conf) {
  const int b = blockIdx.y;
  const int t = threadIdx.x;
  __shared__ unsigned S[256];
  __shared__ float V[256];
  __shared__ unsigned ou[2];
  __shared__ float of[2];
  unsigned p1, p2; int k2, k3;
  float va1, vb1, va2, vb2;
  scan_pair(hist1 + b * 4096, vsum1 + b * 4096, KSEL, S, V, ou, of, p1, k2, va1, vb1);
  scan_pair(hist2 + b * 4096, vsum2 + b * 4096, k2, S, V, ou, of, p2, k3, va2, vb2);
  const float th = finv((p1 << 20) | (p2 << 8));     // 24-bit truncated threshold
  const float Z = sumE[b];
  const float invZ = 1.f / Z;
  const float msum = (va1 + va2 + vb2) * invZ;       // masked sum of soft
  const float invD = 1.f / (msum + 1e-12f);
  const int off = b * NSQ + blockIdx.x * 2048 + t * 8;
#pragma unroll
  for (int i = 0; i < 8; i += 4) {
    float4 v = *(const float4*)&edge[off + i];
    float4 o = make_float4(__expf(v.x * 2.f) * invZ, __expf(v.y * 2.f) * invZ,
                           __expf(v.z * 2.f) * invZ, __expf(v.w * 2.f) * invZ);
    *(float4*)&soft[off + i] = o;
    float cx = v.x >= th ? o.x * invD : 0.f;
    float cy = v.y >= th ? o.y * invD : 0.f;
    float cz = v.z >= th ? o.z * invD : 0.f;
    float cw = v.w >= th ? o.w * invD : 0.f;
    *(float4*)&causal[off + i] = make_float4(cx, cy, cz, cw);
    *(float4*)&conf[off + i]   = make_float4(1.f - cx, 1.f - cy, 1.f - cz, 1.f - cw);
  }
}

extern "C" void kernel_launch(void* const* d_in, const int* in_sizes, int n_in,
                              void* d_out, int out_size, void* d_ws, size_t ws_size,
                              hipStream_t stream) {
  const float* x  = (const float*)d_in[0];
  const float* W1 = (const float*)d_in[1];
  const float* b1 = (const float*)d_in[2];
  const float* W2 = (const float*)d_in[3];
  const float* b2 = (const float*)d_in[4];

  float* out = (float*)d_out;
  float* causal = out;
  float* conf   = out + 1 * 524288;
  float* edge   = out + 2 * 524288;
  float* soft   = out + 3 * 524288;

  float* ws = (float*)d_ws;
  float*    PRBT  = ws;                          // 524288 floats [h][row]
  float*    PCT   = ws + 524288;                 // 524288 floats [h][row]
  unsigned* base  = (unsigned*)(ws + 1048576);
  unsigned* hist1 = base;                        // 8*4096
  float*    vsum1 = (float*)(base + 32768);      // 8*4096
  unsigned* hist2 = base + 65536;                // 8*4096
  float*    vsum2 = (float*)(base + 98304);      // 8*4096
  float*    sumE  = (float*)(base + 131072);     // 8  -> NZERO = 131080

  k_init<<<(NZERO + 255) / 256, 256, 0, stream>>>(base);
  k_gemm<<<dim3(32, 8), 256, 0, stream>>>(x, W1, b1, PRBT, PCT);
  k_edge<<<dim3(8, 4, 8), 256, 0, stream>>>(PRBT, PCT, W2, b2, edge, sumE, hist1, vsum1);
  k_hist2<<<dim3(32, 8), 256, 0, stream>>>(edge, hist1, vsum1, hist2, vsum2);
  k_out<<<dim3(32, 8), 256, 0, stream>>>(edge, sumE, hist1, vsum1, hist2, vsum2,
                                         soft, causal, conf);
}

// Round 7
// 120.361 us; speedup vs baseline: 3.1709x; 1.0512x over previous
//
#include <hip/hip_runtime.h>

#define BB 8
#define NN 256
#define FDIM 1024
#define HDIM 256
#define NSQ 65536            // NN*NN
#define ROWS 2048            // BB*NN
#define KSEL 39321           // int(0.6*NN*NN)
#define NBIN 16384           // 14-bit fkey bins

typedef short s16x8 __attribute__((ext_vector_type(8)));
typedef float f32x4 __attribute__((ext_vector_type(4)));

// ---------- helpers ----------
__device__ __forceinline__ unsigned fkey(float f) {
  unsigned u = __float_as_uint(f);
  return (u & 0x80000000u) ? ~u : (u | 0x80000000u);
}
__device__ __forceinline__ float finv(unsigned k) {
  unsigned u = (k & 0x80000000u) ? (k & 0x7fffffffu) : ~k;
  return __uint_as_float(u);
}
__device__ __forceinline__ unsigned short f2bf(float f) {   // RNE
  unsigned u = __float_as_uint(f);
  unsigned r = (u + 0x7fffu + ((u >> 16) & 1u)) >> 16;
  return (unsigned short)r;
}

// ---------- K0: convert X,W1 -> bf16 + zero gcount/gvsum ----------
// grid 1536: [0,1024) X, [1024,1280) W1, [1280,1536) zero (262144 words).
__global__ __launch_bounds__(256) void k_prep(const float* __restrict__ X,
                                              const float* __restrict__ W1,
                                              unsigned short* __restrict__ XB,
                                              unsigned short* __restrict__ W1B,
                                              unsigned* __restrict__ zero) {
  const int bx = blockIdx.x, t = threadIdx.x;
  if (bx < 1280) {
    const float* src = (bx < 1024) ? X : W1;
    unsigned short* dst = (bx < 1024) ? XB : W1B;
    const int idx = ((bx < 1024 ? bx : bx - 1024) * 256 + t) * 8;
    float4 v0 = *(const float4*)&src[idx];
    float4 v1 = *(const float4*)&src[idx + 4];
    s16x8 o;
    o[0] = (short)f2bf(v0.x); o[1] = (short)f2bf(v0.y); o[2] = (short)f2bf(v0.z); o[3] = (short)f2bf(v0.w);
    o[4] = (short)f2bf(v1.x); o[5] = (short)f2bf(v1.y); o[6] = (short)f2bf(v1.z); o[7] = (short)f2bf(v1.w);
    *(s16x8*)&dst[idx] = o;
  } else {
    const int idx = ((bx - 1280) * 256 + t) * 4;
    *(uint4*)&zero[idx] = make_uint4(0u, 0u, 0u, 0u);
  }
}

// ---------- K1: bf16-MFMA GEMM (pre-converted inputs), TRANSPOSED outputs ----------
// PRBT[h][row] = (x@Wr^T + b1)^T ; PCT[h][row] = (x@Wc^T)^T, row = b*256+n.
#define LDSW 72   // row stride in bf16 elems (64 + 8 pad); 144 B
__global__ __launch_bounds__(256) void k_gemm(const unsigned short* __restrict__ XB,
                                              const unsigned short* __restrict__ W1B,
                                              const float* __restrict__ b1,
                                              float* __restrict__ PRBT,
                                              float* __restrict__ PCT) {
  const int bm = blockIdx.x * 64;
  const int bn = blockIdx.y * 64;         // 0..511
  const int t = threadIdx.x;
  __shared__ short As[64 * LDSW];
  __shared__ short Bs[64 * LDSW];
  const int sr = t >> 2, cg = t & 3;      // staging: row 0..63, 16-elem col group
  const unsigned short* pa = XB + (bm + sr) * FDIM + cg * 16;
  const unsigned short* pb = (bn < 256)
      ? (W1B + (bn + sr) * (2 * FDIM) + cg * 16)
      : (W1B + (bn - 256 + sr) * (2 * FDIM) + FDIM + cg * 16);
  const int w = t >> 6, lane = t & 63;
  const int wm = (w >> 1) * 32, wn = (w & 1) * 32;
  const int q = lane >> 4, m16 = lane & 15;
  f32x4 acc[2][2] = {};
  for (int k0 = 0; k0 < FDIM; k0 += 64) {
    s16x8 a0 = *(const s16x8*)(pa + k0);
    s16x8 a1 = *(const s16x8*)(pa + k0 + 8);
    s16x8 b0 = *(const s16x8*)(pb + k0);
    s16x8 b1v = *(const s16x8*)(pb + k0 + 8);
    __syncthreads();
    *(s16x8*)&As[sr * LDSW + cg * 16]     = a0;
    *(s16x8*)&As[sr * LDSW + cg * 16 + 8] = a1;
    *(s16x8*)&Bs[sr * LDSW + cg * 16]     = b0;
    *(s16x8*)&Bs[sr * LDSW + cg * 16 + 8] = b1v;
    __syncthreads();
    {
      s16x8 af0 = *(s16x8*)&As[(wm + m16) * LDSW + q * 8];
      s16x8 af1 = *(s16x8*)&As[(wm + 16 + m16) * LDSW + q * 8];
      s16x8 bf0 = *(s16x8*)&Bs[(wn + m16) * LDSW + q * 8];
      s16x8 bf1 = *(s16x8*)&Bs[(wn + 16 + m16) * LDSW + q * 8];
      acc[0][0] = __builtin_amdgcn_mfma_f32_16x16x32_bf16(af0, bf0, acc[0][0], 0, 0, 0);
      acc[0][1] = __builtin_amdgcn_mfma_f32_16x16x32_bf16(af0, bf1, acc[0][1], 0, 0, 0);
      acc[1][0] = __builtin_amdgcn_mfma_f32_16x16x32_bf16(af1, bf0, acc[1][0], 0, 0, 0);
      acc[1][1] = __builtin_amdgcn_mfma_f32_16x16x32_bf16(af1, bf1, acc[1][1], 0, 0, 0);
    }
    {
      s16x8 af0 = *(s16x8*)&As[(wm + m16) * LDSW + 32 + q * 8];
      s16x8 af1 = *(s16x8*)&As[(wm + 16 + m16) * LDSW + 32 + q * 8];
      s16x8 bf0 = *(s16x8*)&Bs[(wn + m16) * LDSW + 32 + q * 8];
      s16x8 bf1 = *(s16x8*)&Bs[(wn + 16 + m16) * LDSW + 32 + q * 8];
      acc[0][0] = __builtin_amdgcn_mfma_f32_16x16x32_bf16(af0, bf0, acc[0][0], 0, 0, 0);
      acc[0][1] = __builtin_amdgcn_mfma_f32_16x16x32_bf16(af0, bf1, acc[0][1], 0, 0, 0);
      acc[1][0] = __builtin_amdgcn_mfma_f32_16x16x32_bf16(af1, bf0, acc[1][0], 0, 0, 0);
      acc[1][1] = __builtin_amdgcn_mfma_f32_16x16x32_bf16(af1, bf1, acc[1][1], 0, 0, 0);
    }
  }
#pragma unroll
  for (int rt = 0; rt < 2; ++rt) {
#pragma unroll
    for (int ct = 0; ct < 2; ++ct) {
      const int hn = bn + wn + ct * 16 + m16;       // 0..511
      const int row0 = bm + wm + rt * 16 + q * 4;
      if (hn < 256) {
        const float bias = b1[hn];
        float4 v = make_float4(acc[rt][ct][0] + bias, acc[rt][ct][1] + bias,
                               acc[rt][ct][2] + bias, acc[rt][ct][3] + bias);
        *(float4*)&PRBT[hn * ROWS + row0] = v;
      } else {
        float4 v = make_float4(acc[rt][ct][0], acc[rt][ct][1],
                               acc[rt][ct][2], acc[rt][ct][3]);
        *(float4*)&PCT[(hn - 256) * ROWS + row0] = v;
      }
    }
  }
}

// ---------- K2: edge + 14-bit count/value histogram (single level) ----------
// tile 64(i) x 32(j), 256 threads, 4x2 per thread; grid (8,4,8) = 256 blocks.
__global__ __launch_bounds__(256) void k_edge(const float* __restrict__ PRBT,
                                              const float* __restrict__ PCT,
                                              const float* __restrict__ W2,
                                              const float* __restrict__ b2,
                                              float* __restrict__ edge,
                                              unsigned* __restrict__ gcount,
                                              float* __restrict__ gvsum) {
  const int b = blockIdx.z;
  const int i0 = blockIdx.y * 64, j0 = blockIdx.x * 32;
  const int t = threadIdx.x;
  __shared__ float prs[64][68];        // [h][i]
  __shared__ float pcs[64][36];        // [h][j]
  __shared__ float w2s[HDIM];
  __shared__ unsigned lhc[NBIN / 2];   // packed 2x16-bit counts (32 KB)
  __shared__ float lhv[NBIN];          // value sums (64 KB)
  w2s[t] = W2[t];
#pragma unroll
  for (int i = 0; i < 8; ++i) ((uint4*)lhc)[t + i * 256] = make_uint4(0u, 0u, 0u, 0u);
#pragma unroll
  for (int i = 0; i < 16; ++i) ((float4*)lhv)[t + i * 256] = make_float4(0.f, 0.f, 0.f, 0.f);
  const float bias = b2[0];
  const int tmi = t >> 4, tnj = t & 15;
  float acc[4][2] = {};
  for (int h0 = 0; h0 < HDIM; h0 += 64) {
    __syncthreads();
#pragma unroll
    for (int it = 0; it < 4; ++it) {        // prs: 64h x 64i
      int hh = it * 16 + (t >> 4);
      int ig = t & 15;
      *(float4*)&prs[hh][ig * 4] =
          *(const float4*)&PRBT[(h0 + hh) * ROWS + b * NN + i0 + ig * 4];
    }
#pragma unroll
    for (int it = 0; it < 2; ++it) {        // pcs: 64h x 32j
      int hh = it * 32 + (t >> 3);
      int jg = t & 7;
      *(float4*)&pcs[hh][jg * 4] =
          *(const float4*)&PCT[(h0 + hh) * ROWS + b * NN + j0 + jg * 4];
    }
    __syncthreads();
#pragma unroll 8
    for (int h = 0; h < 64; ++h) {
      const float w = w2s[h0 + h];
      const float4 a = *(const float4*)&prs[h][tmi * 4];
      const float2 c = *(const float2*)&pcs[h][tnj * 2];
      const float ai[4] = {a.x, a.y, a.z, a.w};
#pragma unroll
      for (int i = 0; i < 4; ++i) {
        acc[i][0] += fmaxf(ai[i] + c.x, 0.f) * w;
        acc[i][1] += fmaxf(ai[i] + c.y, 0.f) * w;
      }
    }
  }
  // write edge + histogram (values in registers)
  const int ibase = i0 + tmi * 4, jbase = j0 + tnj * 2;
#pragma unroll
  for (int i = 0; i < 4; ++i) {
    float2 v = make_float2(acc[i][0] + bias, acc[i][1] + bias);
    *(float2*)&edge[b * NSQ + (ibase + i) * NN + jbase] = v;
    float ex = __expf(v.x * 2.f), ey = __expf(v.y * 2.f);
    unsigned bx = fkey(v.x) >> 18, by = fkey(v.y) >> 18;
    atomicAdd(&lhc[bx >> 1], 1u << ((bx & 1) * 16));
    atomicAdd(&lhv[bx], ex);
    atomicAdd(&lhc[by >> 1], 1u << ((by & 1) * 16));
    atomicAdd(&lhv[by], ey);
  }
  __syncthreads();
  unsigned* gc = gcount + b * NBIN;
  float* gv = gvsum + b * NBIN;
#pragma unroll
  for (int i = 0; i < 32; ++i) {
    const int idx = t + i * 256;
    unsigned wv = lhc[idx];
    if (wv) {
      unsigned lo = wv & 0xFFFFu, hi = wv >> 16;
      if (lo) atomicAdd(&gc[2 * idx], lo);
      if (hi) atomicAdd(&gc[2 * idx + 1], hi);
    }
  }
#pragma unroll
  for (int i = 0; i < 64; ++i) {
    const int idx = t + i * 256;
    float vv = lhv[idx];
    if (vv != 0.f) atomicAdd(&gv[idx], vv);
  }
}

// ---------- K3: scan (inline) + soft + causal + conf ----------
__global__ __launch_bounds__(256) void k_out(const float* __restrict__ edge,
                                             const unsigned* __restrict__ gcount,
                                             const float* __restrict__ gvsum,
                                             float* __restrict__ soft,
                                             float* __restrict__ causal,
                                             float* __restrict__ conf) {
  const int b = blockIdx.y;
  const int t = threadIdx.x;
  __shared__ unsigned S[256];
  __shared__ float V[256];
  __shared__ unsigned ou[1];
  __shared__ float of[3];
  const unsigned* hc = gcount + b * NBIN;
  const float* hv = gvsum + b * NBIN;
  unsigned cs = 0; float vs = 0.f;
  for (int i = 0; i < 64; ++i) { cs += hc[t * 64 + i]; vs += hv[t * 64 + i]; }
  S[t] = cs; V[t] = vs;
  __syncthreads();
  for (int off = 1; off < 256; off <<= 1) {     // inclusive suffix sums
    unsigned su = (t + off < 256) ? S[t + off] : 0u;
    float vu = (t + off < 256) ? V[t + off] : 0.f;
    __syncthreads();
    S[t] += su; V[t] += vu;
    __syncthreads();
  }
  if (t == 0) of[2] = V[0];                      // Z = total exp sum
  const int above = (int)(S[t] - cs);
  if (above < KSEL && (int)S[t] >= KSEL) {       // exactly one thread
    int cum = above;
    float vcum = V[t] - vs;
    for (int i = 63; i >= 0; --i) {
      unsigned c = hc[t * 64 + i];
      float v = hv[t * 64 + i];
      cum += (int)c;
      if (cum >= KSEL) { ou[0] = (unsigned)(t * 64 + i); of[0] = vcum; of[1] = v; break; }
      vcum += v;
    }
  }
  __syncthreads();
  const float th = finv(ou[0] << 18);            // 14-bit truncated threshold
  const float Z = of[2];
  const float invZ = 1.f / Z;
  const float msum = (of[0] + of[1]) * invZ;     // masked soft sum (bin-exact)
  const float invD = 1.f / (msum + 1e-12f);
  const int off = b * NSQ + blockIdx.x * 2048 + t * 8;
#pragma unroll
  for (int i = 0; i < 8; i += 4) {
    float4 v = *(const float4*)&edge[off + i];
    float4 o = make_float4(__expf(v.x * 2.f) * invZ, __expf(v.y * 2.f) * invZ,
                           __expf(v.z * 2.f) * invZ, __expf(v.w * 2.f) * invZ);
    *(float4*)&soft[off + i] = o;
    float cx = v.x >= th ? o.x * invD : 0.f;
    float cy = v.y >= th ? o.y * invD : 0.f;
    float cz = v.z >= th ? o.z * invD : 0.f;
    float cw = v.w >= th ? o.w * invD : 0.f;
    *(float4*)&causal[off + i] = make_float4(cx, cy, cz, cw);
    *(float4*)&conf[off + i]   = make_float4(1.f - cx, 1.f - cy, 1.f - cz, 1.f - cw);
  }
}

extern "C" void kernel_launch(void* const* d_in, const int* in_sizes, int n_in,
                              void* d_out, int out_size, void* d_ws, size_t ws_size,
                              hipStream_t stream) {
  const float* x  = (const float*)d_in[0];
  const float* W1 = (const float*)d_in[1];
  const float* b1 = (const float*)d_in[2];
  const float* W2 = (const float*)d_in[3];
  const float* b2 = (const float*)d_in[4];

  float* out = (float*)d_out;
  float* causal = out;
  float* conf   = out + 1 * 524288;
  float* edge   = out + 2 * 524288;
  float* soft   = out + 3 * 524288;

  float* ws = (float*)d_ws;
  float*          PRBT   = ws;                                // 524288 floats
  float*          PCT    = ws + 524288;                       // 524288 floats
  unsigned short* XB     = (unsigned short*)(ws + 1048576);   // 2097152 bf16 (1048576 words)
  unsigned short* W1B    = (unsigned short*)(ws + 2097152);   // 524288 bf16 (262144 words)
  unsigned*       gcount = (unsigned*)(ws + 2359296);         // 8*16384 uints
  float*          gvsum  = (float*)(ws + 2490368);            // 8*16384 floats (zero region: 262144 words total)

  k_prep<<<1536, 256, 0, stream>>>(x, W1, XB, W1B, gcount);
  k_gemm<<<dim3(32, 8), 256, 0, stream>>>(XB, W1B, b1, PRBT, PCT);
  k_edge<<<dim3(8, 4, 8), 256, 0, stream>>>(PRBT, PCT, W2, b2, edge, gcount, gvsum);
  k_out<<<dim3(32, 8), 256, 0, stream>>>(edge, gcount, gvsum, soft, causal, conf);
}

// Round 8
// 106.482 us; speedup vs baseline: 3.5841x; 1.1303x over previous
//
#include <hip/hip_runtime.h>

#define BB 8
#define NN 256
#define FDIM 1024
#define HDIM 256
#define NSQ 65536            // NN*NN
#define ROWS 2048            // BB*NN
#define KSEL 39321           // int(0.6*NN*NN)
#define NBIN 8192            // 13-bit fkey bins

typedef short s16x8 __attribute__((ext_vector_type(8)));
typedef float f32x4 __attribute__((ext_vector_type(4)));

// ---------- helpers ----------
__device__ __forceinline__ unsigned fkey(float f) {
  unsigned u = __float_as_uint(f);
  return (u & 0x80000000u) ? ~u : (u | 0x80000000u);
}
__device__ __forceinline__ float finv(unsigned k) {
  unsigned u = (k & 0x80000000u) ? (k & 0x7fffffffu) : ~k;
  return __uint_as_float(u);
}
__device__ __forceinline__ unsigned short f2bf(float f) {   // RNE
  unsigned u = __float_as_uint(f);
  unsigned r = (u + 0x7fffu + ((u >> 16) & 1u)) >> 16;
  return (unsigned short)r;
}

// ---------- K0: convert X,W1 -> bf16 + zero gcount/gvsum ----------
// grid 1408: [0,1024) X, [1024,1280) W1, [1280,1408) zero (131072 words).
__global__ __launch_bounds__(256) void k_prep(const float* __restrict__ X,
                                              const float* __restrict__ W1,
                                              unsigned short* __restrict__ XB,
                                              unsigned short* __restrict__ W1B,
                                              unsigned* __restrict__ zero) {
  const int bx = blockIdx.x, t = threadIdx.x;
  if (bx < 1280) {
    const float* src = (bx < 1024) ? X : W1;
    unsigned short* dst = (bx < 1024) ? XB : W1B;
    const int idx = ((bx < 1024 ? bx : bx - 1024) * 256 + t) * 8;
    float4 v0 = *(const float4*)&src[idx];
    float4 v1 = *(const float4*)&src[idx + 4];
    s16x8 o;
    o[0] = (short)f2bf(v0.x); o[1] = (short)f2bf(v0.y); o[2] = (short)f2bf(v0.z); o[3] = (short)f2bf(v0.w);
    o[4] = (short)f2bf(v1.x); o[5] = (short)f2bf(v1.y); o[6] = (short)f2bf(v1.z); o[7] = (short)f2bf(v1.w);
    *(s16x8*)&dst[idx] = o;
  } else {
    const int idx = ((bx - 1280) * 256 + t) * 4;
    *(uint4*)&zero[idx] = make_uint4(0u, 0u, 0u, 0u);
  }
}

// ---------- K1: bf16-MFMA GEMM, register-prefetch pipeline, transposed out ----------
// PRBT[h][row] = (x@Wr^T + b1)^T ; PCT[h][row] = (x@Wc^T)^T, row = b*256+n.
#define LDSW 72   // row stride in bf16 elems (64 + 8 pad); 144 B
__global__ __launch_bounds__(256) void k_gemm(const unsigned short* __restrict__ XB,
                                              const unsigned short* __restrict__ W1B,
                                              const float* __restrict__ b1,
                                              float* __restrict__ PRBT,
                                              float* __restrict__ PCT) {
  const int bm = blockIdx.x * 64;
  const int bn = blockIdx.y * 64;         // 0..511
  const int t = threadIdx.x;
  __shared__ short As[64 * LDSW];
  __shared__ short Bs[64 * LDSW];
  const int sr = t >> 2, cg = t & 3;      // staging: row 0..63, 16-elem col group
  const unsigned short* pa = XB + (bm + sr) * FDIM + cg * 16;
  const unsigned short* pb = (bn < 256)
      ? (W1B + (bn + sr) * (2 * FDIM) + cg * 16)
      : (W1B + (bn - 256 + sr) * (2 * FDIM) + FDIM + cg * 16);
  const int w = t >> 6, lane = t & 63;
  const int wm = (w >> 1) * 32, wn = (w & 1) * 32;
  const int q = lane >> 4, m16 = lane & 15;
  f32x4 acc[2][2] = {};
  // prefetch iter 0
  s16x8 ra0 = *(const s16x8*)(pa);
  s16x8 ra1 = *(const s16x8*)(pa + 8);
  s16x8 rb0 = *(const s16x8*)(pb);
  s16x8 rb1 = *(const s16x8*)(pb + 8);
  for (int k0 = 0; k0 < FDIM; k0 += 64) {
    __syncthreads();
    *(s16x8*)&As[sr * LDSW + cg * 16]     = ra0;
    *(s16x8*)&As[sr * LDSW + cg * 16 + 8] = ra1;
    *(s16x8*)&Bs[sr * LDSW + cg * 16]     = rb0;
    *(s16x8*)&Bs[sr * LDSW + cg * 16 + 8] = rb1;
    if (k0 + 64 < FDIM) {                 // prefetch next chunk (overlaps MFMA)
      ra0 = *(const s16x8*)(pa + k0 + 64);
      ra1 = *(const s16x8*)(pa + k0 + 72);
      rb0 = *(const s16x8*)(pb + k0 + 64);
      rb1 = *(const s16x8*)(pb + k0 + 72);
    }
    __syncthreads();
    {
      s16x8 af0 = *(s16x8*)&As[(wm + m16) * LDSW + q * 8];
      s16x8 af1 = *(s16x8*)&As[(wm + 16 + m16) * LDSW + q * 8];
      s16x8 bf0 = *(s16x8*)&Bs[(wn + m16) * LDSW + q * 8];
      s16x8 bf1 = *(s16x8*)&Bs[(wn + 16 + m16) * LDSW + q * 8];
      acc[0][0] = __builtin_amdgcn_mfma_f32_16x16x32_bf16(af0, bf0, acc[0][0], 0, 0, 0);
      acc[0][1] = __builtin_amdgcn_mfma_f32_16x16x32_bf16(af0, bf1, acc[0][1], 0, 0, 0);
      acc[1][0] = __builtin_amdgcn_mfma_f32_16x16x32_bf16(af1, bf0, acc[1][0], 0, 0, 0);
      acc[1][1] = __builtin_amdgcn_mfma_f32_16x16x32_bf16(af1, bf1, acc[1][1], 0, 0, 0);
    }
    {
      s16x8 af0 = *(s16x8*)&As[(wm + m16) * LDSW + 32 + q * 8];
      s16x8 af1 = *(s16x8*)&As[(wm + 16 + m16) * LDSW + 32 + q * 8];
      s16x8 bf0 = *(s16x8*)&Bs[(wn + m16) * LDSW + 32 + q * 8];
      s16x8 bf1 = *(s16x8*)&Bs[(wn + 16 + m16) * LDSW + 32 + q * 8];
      acc[0][0] = __builtin_amdgcn_mfma_f32_16x16x32_bf16(af0, bf0, acc[0][0], 0, 0, 0);
      acc[0][1] = __builtin_amdgcn_mfma_f32_16x16x32_bf16(af0, bf1, acc[0][1], 0, 0, 0);
      acc[1][0] = __builtin_amdgcn_mfma_f32_16x16x32_bf16(af1, bf0, acc[1][0], 0, 0, 0);
      acc[1][1] = __builtin_amdgcn_mfma_f32_16x16x32_bf16(af1, bf1, acc[1][1], 0, 0, 0);
    }
  }
#pragma unroll
  for (int rt = 0; rt < 2; ++rt) {
#pragma unroll
    for (int ct = 0; ct < 2; ++ct) {
      const int hn = bn + wn + ct * 16 + m16;       // 0..511
      const int row0 = bm + wm + rt * 16 + q * 4;
      if (hn < 256) {
        const float bias = b1[hn];
        float4 v = make_float4(acc[rt][ct][0] + bias, acc[rt][ct][1] + bias,
                               acc[rt][ct][2] + bias, acc[rt][ct][3] + bias);
        *(float4*)&PRBT[hn * ROWS + row0] = v;
      } else {
        float4 v = make_float4(acc[rt][ct][0], acc[rt][ct][1],
                               acc[rt][ct][2], acc[rt][ct][3]);
        *(float4*)&PCT[(hn - 256) * ROWS + row0] = v;
      }
    }
  }
}

// ---------- K2: edge + 13-bit count/value histogram ----------
// tile 64(i) x 32(j), 512 threads (8 waves/CU), 2x2 per thread; grid 256.
__global__ __launch_bounds__(512) void k_edge(const float* __restrict__ PRBT,
                                              const float* __restrict__ PCT,
                                              const float* __restrict__ W2,
                                              const float* __restrict__ b2,
                                              float* __restrict__ edge,
                                              unsigned* __restrict__ gcount,
                                              float* __restrict__ gvsum) {
  const int b = blockIdx.z;
  const int i0 = blockIdx.y * 64, j0 = blockIdx.x * 32;
  const int t = threadIdx.x;
  __shared__ float prs[64][68];        // [h][i]
  __shared__ float pcs[64][36];        // [h][j]
  __shared__ float w2s[HDIM];
  __shared__ unsigned lhc[NBIN / 2];   // packed 2x16-bit counts (16 KB)
  __shared__ float lhv[NBIN];          // value sums (32 KB)
  if (t < HDIM) w2s[t] = W2[t];
#pragma unroll
  for (int i = 0; i < 2; ++i) ((uint4*)lhc)[t + i * 512] = make_uint4(0u, 0u, 0u, 0u);
#pragma unroll
  for (int i = 0; i < 4; ++i) ((float4*)lhv)[t + i * 512] = make_float4(0.f, 0.f, 0.f, 0.f);
  const float bias = b2[0];
  const int tmi = t >> 4, tnj = t & 15;     // i-pair 0..31, j-pair 0..15
  float acc[2][2] = {};
  for (int h0 = 0; h0 < HDIM; h0 += 64) {
    __syncthreads();
#pragma unroll
    for (int s = 0; s < 2; ++s) {           // prs: 64h x 64i (1024 float4)
      int idx = t + s * 512;
      int hh = idx >> 4, ig = idx & 15;
      *(float4*)&prs[hh][ig * 4] =
          *(const float4*)&PRBT[(h0 + hh) * ROWS + b * NN + i0 + ig * 4];
    }
    {                                       // pcs: 64h x 32j (512 float4)
      int hh = t >> 3, jg = t & 7;
      *(float4*)&pcs[hh][jg * 4] =
          *(const float4*)&PCT[(h0 + hh) * ROWS + b * NN + j0 + jg * 4];
    }
    __syncthreads();
#pragma unroll 8
    for (int h = 0; h < 64; ++h) {
      const float w = w2s[h0 + h];
      const float2 a = *(const float2*)&prs[h][tmi * 2];
      const float2 c = *(const float2*)&pcs[h][tnj * 2];
      acc[0][0] += fmaxf(a.x + c.x, 0.f) * w;
      acc[0][1] += fmaxf(a.x + c.y, 0.f) * w;
      acc[1][0] += fmaxf(a.y + c.x, 0.f) * w;
      acc[1][1] += fmaxf(a.y + c.y, 0.f) * w;
    }
  }
  // write edge + histogram (values in registers)
  const int ibase = i0 + tmi * 2, jbase = j0 + tnj * 2;
#pragma unroll
  for (int i = 0; i < 2; ++i) {
    float2 v = make_float2(acc[i][0] + bias, acc[i][1] + bias);
    *(float2*)&edge[b * NSQ + (ibase + i) * NN + jbase] = v;
    float ex = __expf(v.x * 2.f), ey = __expf(v.y * 2.f);
    unsigned bx = fkey(v.x) >> 19, by = fkey(v.y) >> 19;
    atomicAdd(&lhc[bx >> 1], 1u << ((bx & 1) * 16));
    atomicAdd(&lhv[bx], ex);
    atomicAdd(&lhc[by >> 1], 1u << ((by & 1) * 16));
    atomicAdd(&lhv[by], ey);
  }
  __syncthreads();
  unsigned* gc = gcount + b * NBIN;
  float* gv = gvsum + b * NBIN;
#pragma unroll
  for (int i = 0; i < 8; ++i) {
    const int idx = t + i * 512;
    unsigned wv = lhc[idx];
    if (wv) {
      unsigned lo = wv & 0xFFFFu, hi = wv >> 16;
      if (lo) atomicAdd(&gc[2 * idx], lo);
      if (hi) atomicAdd(&gc[2 * idx + 1], hi);
    }
  }
#pragma unroll
  for (int i = 0; i < 16; ++i) {
    const int idx = t + i * 512;
    float vv = lhv[idx];
    if (vv != 0.f) atomicAdd(&gv[idx], vv);
  }
}

// ---------- K3: scan (inline) + soft + causal + conf ----------
__global__ __launch_bounds__(256) void k_out(const float* __restrict__ edge,
                                             const unsigned* __restrict__ gcount,
                                             const float* __restrict__ gvsum,
                                             float* __restrict__ soft,
                                             float* __restrict__ causal,
                                             float* __restrict__ conf) {
  const int b = blockIdx.y;
  const int t = threadIdx.x;
  __shared__ unsigned S[256];
  __shared__ float V[256];
  __shared__ unsigned ou[1];
  __shared__ float of[3];
  const unsigned* hc = gcount + b * NBIN;
  const float* hv = gvsum + b * NBIN;
  unsigned cs = 0; float vs = 0.f;
  for (int i = 0; i < 32; ++i) { cs += hc[t * 32 + i]; vs += hv[t * 32 + i]; }
  S[t] = cs; V[t] = vs;
  __syncthreads();
  for (int off = 1; off < 256; off <<= 1) {     // inclusive suffix sums
    unsigned su = (t + off < 256) ? S[t + off] : 0u;
    float vu = (t + off < 256) ? V[t + off] : 0.f;
    __syncthreads();
    S[t] += su; V[t] += vu;
    __syncthreads();
  }
  if (t == 0) of[2] = V[0];                      // Z = total exp sum
  const int above = (int)(S[t] - cs);
  if (above < KSEL && (int)S[t] >= KSEL) {       // exactly one thread
    int cum = above;
    float vcum = V[t] - vs;
    for (int i = 31; i >= 0; --i) {
      unsigned c = hc[t * 32 + i];
      float v = hv[t * 32 + i];
      cum += (int)c;
      if (cum >= KSEL) { ou[0] = (unsigned)(t * 32 + i); of[0] = vcum; of[1] = v; break; }
      vcum += v;
    }
  }
  __syncthreads();
  const float th = finv(ou[0] << 19);            // 13-bit truncated threshold
  const float Z = of[2];
  const float invZ = 1.f / Z;
  const float msum = (of[0] + of[1]) * invZ;     // masked soft sum (bin-exact)
  const float invD = 1.f / (msum + 1e-12f);
  const int off = b * NSQ + blockIdx.x * 2048 + t * 8;
#pragma unroll
  for (int i = 0; i < 8; i += 4) {
    float4 v = *(const float4*)&edge[off + i];
    float4 o = make_float4(__expf(v.x * 2.f) * invZ, __expf(v.y * 2.f) * invZ,
                           __expf(v.z * 2.f) * invZ, __expf(v.w * 2.f) * invZ);
    *(float4*)&soft[off + i] = o;
    float cx = v.x >= th ? o.x * invD : 0.f;
    float cy = v.y >= th ? o.y * invD : 0.f;
    float cz = v.z >= th ? o.z * invD : 0.f;
    float cw = v.w >= th ? o.w * invD : 0.f;
    *(float4*)&causal[off + i] = make_float4(cx, cy, cz, cw);
    *(float4*)&conf[off + i]   = make_float4(1.f - cx, 1.f - cy, 1.f - cz, 1.f - cw);
  }
}

extern "C" void kernel_launch(void* const* d_in, const int* in_sizes, int n_in,
                              void* d_out, int out_size, void* d_ws, size_t ws_size,
                              hipStream_t stream) {
  const float* x  = (const float*)d_in[0];
  const float* W1 = (const float*)d_in[1];
  const float* b1 = (const float*)d_in[2];
  const float* W2 = (const float*)d_in[3];
  const float* b2 = (const float*)d_in[4];

  float* out = (float*)d_out;
  float* causal = out;
  float* conf   = out + 1 * 524288;
  float* edge   = out + 2 * 524288;
  float* soft   = out + 3 * 524288;

  float* ws = (float*)d_ws;
  float*          PRBT   = ws;                                // 524288 floats
  float*          PCT    = ws + 524288;                       // 524288 floats
  unsigned short* XB     = (unsigned short*)(ws + 1048576);   // 2097152 bf16
  unsigned short* W1B    = (unsigned short*)(ws + 2097152);   // 524288 bf16
  unsigned*       gcount = (unsigned*)(ws + 2359296);         // 8*8192 uints
  float*          gvsum  = (float*)(ws + 2424832);            // 8*8192 floats (zero: 131072 words)

  k_prep<<<1408, 256, 0, stream>>>(x, W1, XB, W1B, gcount);
  k_gemm<<<dim3(32, 8), 256, 0, stream>>>(XB, W1B, b1, PRBT, PCT);
  k_edge<<<dim3(8, 4, 8), 512, 0, stream>>>(PRBT, PCT, W2, b2, edge, gcount, gvsum);
  k_out<<<dim3(32, 8), 256, 0, stream>>>(edge, gcount, gvsum, soft, causal, conf);
}